// Round 1
// baseline (623.103 us; speedup 1.0000x reference)
//
#include <hip/hip_runtime.h>
#include <math.h>

typedef short s16;
typedef __attribute__((ext_vector_type(8))) short short8;
typedef __attribute__((ext_vector_type(4))) float f32x4;

__device__ __forceinline__ float bf2f_lo(unsigned u){ return __builtin_bit_cast(float, u << 16); }
__device__ __forceinline__ float bf2f_hi(unsigned u){ return __builtin_bit_cast(float, u & 0xffff0000u); }
__device__ __forceinline__ float bf2f(unsigned short h){ return __builtin_bit_cast(float, (unsigned)h << 16); }
__device__ __forceinline__ s16 f2bf(float f){
  unsigned u = __builtin_bit_cast(unsigned, f);
  u += 0x7fffu + ((u >> 16) & 1u);
  return (s16)(u >> 16);
}
__device__ __forceinline__ void unpack8(int4 v, float* f){
  unsigned a=(unsigned)v.x, b=(unsigned)v.y, c=(unsigned)v.z, d=(unsigned)v.w;
  f[0]=bf2f_lo(a); f[1]=bf2f_hi(a); f[2]=bf2f_lo(b); f[3]=bf2f_hi(b);
  f[4]=bf2f_lo(c); f[5]=bf2f_hi(c); f[6]=bf2f_lo(d); f[7]=bf2f_hi(d);
}
// async global->LDS 16B: lds dest is wave-uniform base + lane*16
__device__ __forceinline__ void gl2lds16(const s16* g, s16* l){
  __builtin_amdgcn_global_load_lds((const __attribute__((address_space(1))) void*)g,
                                   (__attribute__((address_space(3))) void*)l, 16, 0, 0);
}

// ---------------- LayerNorm (fp32 in) -> bf16 out, D=1024, 1 block/row ------
__global__ __launch_bounds__(256) void ln_bf16(const float* __restrict__ x,
                                               const float* __restrict__ w,
                                               const float* __restrict__ b,
                                               s16* __restrict__ out){
  int row = blockIdx.x; int t = threadIdx.x;
  const float* xr = x + (size_t)row * 1024;
  float4 v = *(const float4*)(xr + t*4);
  float s = v.x + v.y + v.z + v.w;
  float ss = v.x*v.x + v.y*v.y + v.z*v.z + v.w*v.w;
  for (int o = 32; o > 0; o >>= 1){ s += __shfl_down(s, o, 64); ss += __shfl_down(ss, o, 64); }
  __shared__ float red[8];
  int wid = t >> 6, lane = t & 63;
  if (lane == 0){ red[wid] = s; red[4+wid] = ss; }
  __syncthreads();
  if (t == 0){
    float S = red[0]+red[1]+red[2]+red[3];
    float SS = red[4]+red[5]+red[6]+red[7];
    red[0] = S * (1.f/1024.f);
    red[1] = SS * (1.f/1024.f);
  }
  __syncthreads();
  float mu = red[0];
  float var = red[1] - mu*mu;
  float rstd = rsqrtf(var + 1e-6f);
  float vv[4] = {v.x, v.y, v.z, v.w};
  short4 o4;
  s16 tmp[4];
  #pragma unroll
  for (int i = 0; i < 4; ++i){
    int c = t*4 + i;
    float val = (vv[i] - mu) * rstd * w[c] + b[c];
    tmp[i] = f2bf(val);
  }
  o4.x = tmp[0]; o4.y = tmp[1]; o4.z = tmp[2]; o4.w = tmp[3];
  *(short4*)(out + (size_t)row*1024 + t*4) = o4;
}

// ---------------- transpose-convert fp32 W[K,N] -> bf16 Wt[N,K], with scale --
__global__ __launch_bounds__(256) void conv_t(const float* __restrict__ W,
                                              s16* __restrict__ Wt,
                                              int K, int N, float scale){
  __shared__ float tile[32][33];
  int n0 = blockIdx.x * 32, k0 = blockIdx.y * 32;
  int tx = threadIdx.x & 31, ty = threadIdx.x >> 5;   // ty 0..7
  #pragma unroll
  for (int i = 0; i < 4; ++i){
    int r = ty + i*8;
    tile[r][tx] = W[(size_t)(k0 + r)*N + n0 + tx];
  }
  __syncthreads();
  #pragma unroll
  for (int i = 0; i < 4; ++i){
    int r = ty + i*8;
    Wt[(size_t)(n0 + r)*K + k0 + tx] = f2bf(tile[tx][r] * scale);
  }
}

// XCD swizzle: 1D grid, tiles_y M-tiles (divisible by 8). Each XCD owns a
// disjoint M-row stripe (A fetched once, per-XCD L2); N iterated slowly so
// the B-slab stays hot across sy consecutive on-XCD blocks.
__device__ __forceinline__ void xcd_tile(int tiles_y, int& tx, int& ty){
  int id = blockIdx.x;
  int sy = tiles_y >> 3;
  int xcd = id & 7, p = id >> 3;
  ty = xcd * sy + (p % sy);
  tx = p / sy;
}

// ============ 256x256 8-phase bf16 GEMM (T1+T2+T3+T4+T5), BK=64 =============
// C[M,N] = A[M,K] @ Bt[N,K]^T. 512 threads (8 waves 2Mx4N), 128KB LDS dbuf.
// LDS halves: A0=rows 0..127, A1=128..255, B0=cols 0..127, B1=128..255.
// Wave (wm,wn): rows wm*64 + mh*128 + m*16, cols wn*32 + nh*128 + nj*16
//   -> A-half mh read only at its mh-phase; B-half nh only at its nh-phase.
// Phases per K-tile: (mh,nh) = (0,0),(0,1),(1,0),(1,1).
//   new ds-reads: P1: A(mh0)+B(nh0)=12, P2: B(nh1)=4, P3: A(mh1)=8, P4: 0.
// Stage order (during tile t, for t+1): P1->A0, P2->B0, P3->B1, P4->A1.
// Steady vmcnt(6) at P1..P3 (proof: queue [A0,B0,B1,A1]=8 at P1 entry; +2
// issued; wait->6 completes exactly A0,B0; etc). Epilogue drains 4->2->0.
// LDS swizzle (both-sides, rule 21): phys c8 = c8 ^ (row&7); writes via
// pre-swizzled GLOBAL source (gl2lds dest stays linear), reads XOR the addr.
// -> ds_read_b128: 8 lanes / 16B-slot group = 2-way/bank = conflict-free.
__global__ __launch_bounds__(512,2) void gemm256(const s16* __restrict__ A,
                                                 const s16* __restrict__ Bt,
                                                 int N, int K,
                                                 s16* __restrict__ Cb,
                                                 const float* __restrict__ bias,
                                                 int flags, int tiles_y){
  __shared__ s16 lds[2*4*8192];   // [buf][half: A0,A1,B0,B1][128*64]
  int t = threadIdx.x;
  int tx, ty; xcd_tile(tiles_y, tx, ty);
  int m0 = ty * 256, n0 = tx * 256;
  int w = t >> 6, lane = t & 63;
  int wm = w >> 2, wn = w & 3;         // 2M x 4N
  int lrow = lane & 15, lq = lane >> 4;
  int s = lrow & 7;

  // staging: thread i -> row (i>>3) of a 64-row round, col-group g (swizzled)
  int grow = t >> 3;                   // 0..63
  int g = (t & 7) ^ (grow & 7);
  const s16* Ag = A  + (size_t)(m0 + grow) * K + g*8;
  const s16* Bg = Bt + (size_t)(n0 + grow) * K + g*8;
  int wo = w * 512;                    // wave dest offset (elems) in 8KB round

  // frag read bases (elems within a half) + swizzled col-group offsets
  int abase = (wm*64 + lrow) * 64;
  int bbase = (wn*32 + lrow) * 64;
  int sw0 = ((lq ^ s) << 3);           // kk=0  -> c8 = lq
  int sw1 = (((4 + lq) ^ s) << 3);     // kk=32 -> c8 = 4+lq

  f32x4 acc[2][4][2][2];
  #pragma unroll
  for (int a = 0; a < 2; ++a)
    #pragma unroll
    for (int b = 0; b < 4; ++b)
      #pragma unroll
      for (int c = 0; c < 2; ++c)
        #pragma unroll
        for (int d = 0; d < 2; ++d) acc[a][b][c][d] = (f32x4){0.f,0.f,0.f,0.f};

  short8 af[2][4];        // [kk-slot][m], reloaded per mh
  short8 bfr[2][2][2];    // [nh][kk-slot][nj], both nh kept live

#define STG_A(buf,h,kt) do{ \
    gl2lds16(Ag + (size_t)((h)*128    )*K + (kt)*64, lds + ((buf)*4+(h))*8192 + wo); \
    gl2lds16(Ag + (size_t)((h)*128+ 64)*K + (kt)*64, lds + ((buf)*4+(h))*8192 + 4096 + wo); }while(0)
#define STG_B(buf,nh,kt) do{ \
    gl2lds16(Bg + (size_t)((nh)*128    )*K + (kt)*64, lds + ((buf)*4+2+(nh))*8192 + wo); \
    gl2lds16(Bg + (size_t)((nh)*128+ 64)*K + (kt)*64, lds + ((buf)*4+2+(nh))*8192 + 4096 + wo); }while(0)
#define RD_A(buf,mh) do{ const s16* p_ = lds + ((buf)*4+(mh))*8192 + abase; \
    _Pragma("unroll") for (int m_ = 0; m_ < 4; ++m_){ \
      af[0][m_] = *(const short8*)(p_ + m_*1024 + sw0); \
      af[1][m_] = *(const short8*)(p_ + m_*1024 + sw1); } }while(0)
#define RD_B(buf,nh) do{ const s16* p_ = lds + ((buf)*4+2+(nh))*8192 + bbase; \
    _Pragma("unroll") for (int n_ = 0; n_ < 2; ++n_){ \
      bfr[nh][0][n_] = *(const short8*)(p_ + n_*1024 + sw0); \
      bfr[nh][1][n_] = *(const short8*)(p_ + n_*1024 + sw1); } }while(0)
#define MFMA_Q(mh,nh) do{ __builtin_amdgcn_s_setprio(1); \
    _Pragma("unroll") for (int kk_ = 0; kk_ < 2; ++kk_) \
      _Pragma("unroll") for (int m_ = 0; m_ < 4; ++m_) \
        _Pragma("unroll") for (int n_ = 0; n_ < 2; ++n_) \
          acc[mh][m_][nh][n_] = __builtin_amdgcn_mfma_f32_16x16x32_bf16( \
              af[kk_][m_], bfr[nh][kk_][n_], acc[mh][m_][nh][n_], 0, 0, 0); \
    __builtin_amdgcn_s_setprio(0); }while(0)
#define VM6() asm volatile("s_waitcnt vmcnt(6)" ::: "memory")
#define BARR() asm volatile("s_barrier" ::: "memory")

  int NT = K >> 6;
  // prologue: tile 0 into buf0, issue order A0,B0,B1,A1 (matches wait math)
  STG_A(0,0,0); STG_B(0,0,0); STG_B(0,1,0); STG_A(0,1,0);

  for (int kt = 0; kt < NT-1; ++kt){
    int cb = kt & 1, nb = cb ^ 1;
    // P1 (mh0,nh0)
    STG_A(nb,0,kt+1);
    VM6(); BARR();
    RD_A(cb,0); RD_B(cb,0);
    MFMA_Q(0,0);
    BARR();
    // P2 (mh0,nh1)
    STG_B(nb,0,kt+1);
    VM6(); BARR();
    RD_B(cb,1);
    MFMA_Q(0,1);
    BARR();
    // P3 (mh1,nh0)
    STG_B(nb,1,kt+1);
    VM6(); BARR();
    RD_A(cb,1);
    MFMA_Q(1,0);
    BARR();
    // P4 (mh1,nh1)
    STG_A(nb,1,kt+1);
    BARR();
    MFMA_Q(1,1);
    BARR();
  }
  { // epilogue tile NT-1: no staging; drain 4 -> 2 -> 0
    int cb = (NT-1) & 1;
    asm volatile("s_waitcnt vmcnt(4)" ::: "memory"); BARR();
    RD_A(cb,0); RD_B(cb,0); MFMA_Q(0,0); BARR();
    asm volatile("s_waitcnt vmcnt(2)" ::: "memory"); BARR();
    RD_B(cb,1); MFMA_Q(0,1); BARR();
    asm volatile("s_waitcnt vmcnt(0)" ::: "memory"); BARR();
    RD_A(cb,1); MFMA_Q(1,0); BARR();
    MFMA_Q(1,1);
  }
#undef STG_A
#undef STG_B
#undef RD_A
#undef RD_B
#undef MFMA_Q
#undef VM6
#undef BARR

  bool do_gelu = flags & 1;
  #pragma unroll
  for (int nh = 0; nh < 2; ++nh){
    #pragma unroll
    for (int nj = 0; nj < 2; ++nj){
      int col = n0 + wn*32 + nh*128 + nj*16 + lrow;
      float bcol = bias ? bias[col] : 0.f;
      #pragma unroll
      for (int mh = 0; mh < 2; ++mh){
        #pragma unroll
        for (int m = 0; m < 4; ++m){
          int row_base = m0 + wm*64 + mh*128 + m*16 + lq*4;
          #pragma unroll
          for (int r = 0; r < 4; ++r){
            float val = acc[mh][m][nh][nj][r] + bcol;
            if (do_gelu) val = 0.5f * val * (1.f + erff(val * 0.70710678118654752f));
            Cb[(size_t)(row_base + r) * N + col] = f2bf(val);
          }
        }
      }
    }
  }
}

// ---------------- bf16 MFMA GEMM 64x128 tile, BK=64 dual-buffer --------------
// 1D grid = (N/128)*(M/64); tiles_y = M/64. Wave w owns cols [32w,32w+32).
__global__ __launch_bounds__(256,2) void gemm_nt_h(const s16* __restrict__ A,
                                                   const s16* __restrict__ Bt,
                                                   int M, int N, int K, int ldb,
                                                   float* __restrict__ Cf,
                                                   s16* __restrict__ Cb,
                                                   const float* __restrict__ bias,
                                                   const float* __restrict__ resid,
                                                   int flags, int tiles_y){
  __shared__ s16 As0[64*32], As1[64*32];
  __shared__ s16 Bs0[128*32], Bs1[128*32];
  int t = threadIdx.x;
  int tx, ty; xcd_tile(tiles_y, tx, ty);
  int m0 = ty * 64, n0 = tx * 128;
  int w = t >> 6, lane = t & 63;
  int lrow = lane & 15, lq = lane >> 4;
  f32x4 acc[4][2];
  #pragma unroll
  for (int i = 0; i < 4; ++i)
    #pragma unroll
    for (int j = 0; j < 2; ++j) acc[i][j] = (f32x4){0.f,0.f,0.f,0.f};

  const s16* Ag = A  + (size_t)(m0 + (t>>2)) * K   + (t&3)*8;
  const s16* Bg = Bt + (size_t)(n0 + (t>>2)) * ldb + (t&3)*8;
  int wo = w*512;

  for (int k0 = 0; k0 < K; k0 += 64){
    __syncthreads();
    gl2lds16(Ag + k0,      As0 + wo);
    gl2lds16(Ag + k0 + 32, As1 + wo);
    gl2lds16(Bg + k0,                       Bs0 + wo);
    gl2lds16(Bg + (size_t)64*ldb + k0,      Bs0 + 2048 + wo);
    gl2lds16(Bg + k0 + 32,                  Bs1 + wo);
    gl2lds16(Bg + (size_t)64*ldb + k0 + 32, Bs1 + 2048 + wo);
    __syncthreads();
    short8 af[4], bfr[2];
    #pragma unroll
    for (int mi = 0; mi < 4; ++mi)
      af[mi] = *(short8*)&As0[(mi*16 + lrow)*32 + lq*8];
    #pragma unroll
    for (int ni = 0; ni < 2; ++ni)
      bfr[ni] = *(short8*)&Bs0[(w*32 + ni*16 + lrow)*32 + lq*8];
    #pragma unroll
    for (int mi = 0; mi < 4; ++mi)
      #pragma unroll
      for (int ni = 0; ni < 2; ++ni)
        acc[mi][ni] = __builtin_amdgcn_mfma_f32_16x16x32_bf16(af[mi], bfr[ni], acc[mi][ni], 0, 0, 0);
    #pragma unroll
    for (int mi = 0; mi < 4; ++mi)
      af[mi] = *(short8*)&As1[(mi*16 + lrow)*32 + lq*8];
    #pragma unroll
    for (int ni = 0; ni < 2; ++ni)
      bfr[ni] = *(short8*)&Bs1[(w*32 + ni*16 + lrow)*32 + lq*8];
    #pragma unroll
    for (int mi = 0; mi < 4; ++mi)
      #pragma unroll
      for (int ni = 0; ni < 2; ++ni)
        acc[mi][ni] = __builtin_amdgcn_mfma_f32_16x16x32_bf16(af[mi], bfr[ni], acc[mi][ni], 0, 0, 0);
  }

  bool do_gelu = flags & 1;
  bool out_bf = flags & 2;
  #pragma unroll
  for (int mi = 0; mi < 4; ++mi){
    #pragma unroll
    for (int ni = 0; ni < 2; ++ni){
      int gcol = n0 + w*32 + ni*16 + lrow;
      float bcol = bias ? bias[gcol] : 0.f;
      int grow_base = m0 + mi*16 + lq*4;
      #pragma unroll
      for (int r = 0; r < 4; ++r){
        int grow = grow_base + r;
        float val = acc[mi][ni][r] + bcol;
        if (do_gelu) val = 0.5f * val * (1.f + erff(val * 0.70710678118654752f));
        if (resid) val += resid[(size_t)grow * N + gcol];
        if (out_bf) Cb[(size_t)grow * N + gcol] = f2bf(val);
        else        Cf[(size_t)grow * N + gcol] = val;
      }
    }
  }
}

// ---------------- retention 2a (per batch): U_t[dv][dk] = (d_k*k (x) v)^T ----
// grid 512 = h(8) + n(64); k,v from fused qkv (row stride 4096)
__global__ __launch_bounds__(256,2) void ret_chunksum(const s16* __restrict__ k,
                                                      const s16* __restrict__ v,
                                                      s16* __restrict__ U){
  int bi = blockIdx.x;
  int h = bi & 7, n = bi >> 3;
  int t = threadIdx.x;
  __shared__ s16 ks[128*72];   // ks[dk][s], d_k decay folded
  __shared__ s16 vs[256*72];   // vs[dv][s]
  float log2b = log2f(1.f - exp2f(-5.f - (float)h));
  const s16* kbase = k + (size_t)(n*64)*4096 + h*128;
  const s16* vbase = v + (size_t)(n*64)*4096 + h*256;
  #pragma unroll
  for (int i = 0; i < 4; ++i){
    int e = i*2048 + t*8;
    int s = e >> 7, dk = e & 127;
    int4 kv = *(const int4*)(kbase + (size_t)s*4096 + dk);
    float f[8]; unpack8(kv, f);
    float dec = exp2f(log2b * (float)(63 - s));
    #pragma unroll
    for (int j = 0; j < 8; ++j) ks[(dk+j)*72 + s] = f2bf(f[j]*dec);
  }
  #pragma unroll
  for (int i = 0; i < 8; ++i){
    int e = i*2048 + t*8;
    int s = e >> 8, dv = e & 255;
    int4 vv = *(const int4*)(vbase + (size_t)s*4096 + dv);
    s16 tmp[8]; *(int4*)tmp = vv;
    #pragma unroll
    for (int j = 0; j < 8; ++j) vs[(dv+j)*72 + s] = tmp[j];
  }
  __syncthreads();
  int w = t >> 6, lane = t & 63;
  int m0w = w*64;   // dv rows, 4 tiles per wave
  int lrow = lane & 15, lq = lane >> 4;
  f32x4 acc[4][8];
  #pragma unroll
  for (int mi = 0; mi < 4; ++mi)
    #pragma unroll
    for (int ni = 0; ni < 8; ++ni) acc[mi][ni] = (f32x4){0.f,0.f,0.f,0.f};
  #pragma unroll
  for (int kk = 0; kk < 64; kk += 32){
    short8 af[4], bfr[8];
    #pragma unroll
    for (int mi = 0; mi < 4; ++mi)
      af[mi] = *(short8*)&vs[(m0w + mi*16 + lrow)*72 + kk + lq*8];
    #pragma unroll
    for (int ni = 0; ni < 8; ++ni)
      bfr[ni] = *(short8*)&ks[(ni*16 + lrow)*72 + kk + lq*8];
    #pragma unroll
    for (int mi = 0; mi < 4; ++mi)
      #pragma unroll
      for (int ni = 0; ni < 8; ++ni)
        acc[mi][ni] = __builtin_amdgcn_mfma_f32_16x16x32_bf16(af[mi], bfr[ni], acc[mi][ni], 0, 0, 0);
  }
  s16* Ub = U + ((size_t)(h*64 + n))*32768;
  #pragma unroll
  for (int mi = 0; mi < 4; ++mi)
    #pragma unroll
    for (int ni = 0; ni < 8; ++ni)
      #pragma unroll
      for (int r = 0; r < 4; ++r){
        int row = m0w + mi*16 + lq*4 + r;   // dv
        int col = ni*16 + lrow;             // dk
        Ub[(size_t)row*128 + col] = f2bf(acc[mi][ni][r]);
      }
}

// ---------------- retention 2b (per batch): in-place decay prefix scan -------
__global__ __launch_bounds__(256) void ret_scan(s16* __restrict__ US){
  int tid = blockIdx.x*256 + threadIdx.x;       // 32768 threads
  int h = tid >> 12;
  int rem = tid & 4095;
  int dv = rem >> 4, dk0 = (rem & 15)*8;
  float log2b = log2f(1.f - exp2f(-5.f - (float)h));
  float dc = exp2f(log2b * 64.f);
  s16* base = US + (size_t)h*64*32768 + (size_t)dv*128 + dk0;
  float acc[8] = {0.f,0.f,0.f,0.f,0.f,0.f,0.f,0.f};
  #pragma unroll 4
  for (int n = 0; n < 64; ++n){
    s16* p = base + (size_t)n*32768;
    int4 u4 = *(const int4*)p;
    float uf[8]; unpack8(u4, uf);
    s16 sb[8];
    #pragma unroll
    for (int j = 0; j < 8; ++j) sb[j] = f2bf(acc[j]);
    *(int4*)p = *(int4*)sb;
    #pragma unroll
    for (int j = 0; j < 8; ++j) acc[j] = acc[j]*dc + uf[j];
  }
}

// ---------------- retention fused (per batch): O = mask(qk^T)@v + dq*(q@S) ---
// grid 512 = h(8) + n(64). q,k,v from fused qkv (stride 4096); S_t [h][n][256][128]
__global__ __launch_bounds__(256,2) void ret_attn(const s16* __restrict__ q,
                                                  const s16* __restrict__ k,
                                                  const s16* __restrict__ v,
                                                  const s16* __restrict__ S,
                                                  s16* __restrict__ o){
  int bi = blockIdx.x;
  int h = bi & 7, n = bi >> 3;
  int t = threadIdx.x;
  int w = t >> 6, lane = t & 63;
  int lrow = lane & 15, lq = lane >> 4;
  float log2b = log2f(1.f - exp2f(-5.f - (float)h));
  __shared__ s16 As[64*72];    // masked scores, A-operand staging
  __shared__ s16 vs[256*72];   // v^T [dv][s]

  // stage v transposed
  const s16* vbase = v + (size_t)(n*64)*4096 + h*256;
  #pragma unroll
  for (int i = 0; i < 8; ++i){
    int e = i*2048 + t*8;
    int s = e >> 8, dv = e & 255;
    int4 vv = *(const int4*)(vbase + (size_t)s*4096 + dv);
    s16 tmp[8]; *(int4*)tmp = vv;
    #pragma unroll
    for (int j = 0; j < 8; ++j) vs[(dv+j)*72 + s] = tmp[j];
  }

  // phase 1: wave w computes A[:, 16w:16w+16] = q @ k^T, masked
  const s16* qbase = q + (size_t)(n*64)*4096 + h*128;
  const s16* kbase = k + (size_t)(n*64)*4096 + h*128;
  short8 qf[4][4];   // [row-tile][kstep], reused in phase 2
  #pragma unroll
  for (int ti = 0; ti < 4; ++ti)
    #pragma unroll
    for (int c = 0; c < 4; ++c)
      qf[ti][c] = *(const short8*)(qbase + (size_t)(ti*16 + lrow)*4096 + c*32 + lq*8);
  short8 kf[4];
  #pragma unroll
  for (int c = 0; c < 4; ++c)
    kf[c] = *(const short8*)(kbase + (size_t)(16*w + lrow)*4096 + c*32 + lq*8);
  #pragma unroll
  for (int ti = 0; ti < 4; ++ti){
    f32x4 acc_a = (f32x4){0.f,0.f,0.f,0.f};
    #pragma unroll
    for (int c = 0; c < 4; ++c)
      acc_a = __builtin_amdgcn_mfma_f32_16x16x32_bf16(qf[ti][c], kf[c], acc_a, 0, 0, 0);
    #pragma unroll
    for (int r = 0; r < 4; ++r){
      int ti_idx = ti*16 + lq*4 + r;
      int s_idx = 16*w + lrow;
      int d = ti_idx - s_idx;
      float val = (d >= 0) ? acc_a[r] * exp2f(log2b * (float)d) : 0.f;
      As[ti_idx*72 + s_idx] = f2bf(val);
    }
  }
  __syncthreads();

  // phase 2: wave w owns dv cols [64w, 64w+64)
  f32x4 acc[4][4];
  #pragma unroll
  for (int mi = 0; mi < 4; ++mi)
    #pragma unroll
    for (int nj = 0; nj < 4; ++nj) acc[mi][nj] = (f32x4){0.f,0.f,0.f,0.f};

  // q @ S  (K = 128)
  const s16* Sbase = S + ((size_t)(h*64 + n)*256 + w*64)*128;
  #pragma unroll
  for (int c = 0; c < 4; ++c){
    short8 bf[4];
    #pragma unroll
    for (int nj = 0; nj < 4; ++nj)
      bf[nj] = *(const short8*)(Sbase + (size_t)(nj*16 + lrow)*128 + c*32 + lq*8);
    #pragma unroll
    for (int mi = 0; mi < 4; ++mi)
      #pragma unroll
      for (int nj = 0; nj < 4; ++nj)
        acc[mi][nj] = __builtin_amdgcn_mfma_f32_16x16x32_bf16(qf[mi][c], bf[nj], acc[mi][nj], 0, 0, 0);
  }
  // scale by d_q = b^(row+1)
  #pragma unroll
  for (int mi = 0; mi < 4; ++mi){
    #pragma unroll
    for (int r = 0; r < 4; ++r){
      float dq = exp2f(log2b * (float)(mi*16 + lq*4 + r + 1));
      #pragma unroll
      for (int nj = 0; nj < 4; ++nj) acc[mi][nj][r] *= dq;
    }
  }
  // A @ v  (K = 64)
  #pragma unroll
  for (int c = 0; c < 2; ++c){
    short8 af[4], bf[4];
    #pragma unroll
    for (int mi = 0; mi < 4; ++mi)
      af[mi] = *(short8*)&As[(mi*16 + lrow)*72 + c*32 + lq*8];
    #pragma unroll
    for (int nj = 0; nj < 4; ++nj)
      bf[nj] = *(short8*)&vs[(w*64 + nj*16 + lrow)*72 + c*32 + lq*8];
    #pragma unroll
    for (int mi = 0; mi < 4; ++mi)
      #pragma unroll
      for (int nj = 0; nj < 4; ++nj)
        acc[mi][nj] = __builtin_amdgcn_mfma_f32_16x16x32_bf16(af[mi], bf[nj], acc[mi][nj], 0, 0, 0);
  }
  // write O
  s16* obase = o + (size_t)(n*64)*2048 + h*256;
  #pragma unroll
  for (int mi = 0; mi < 4; ++mi)
    #pragma unroll
    for (int nj = 0; nj < 4; ++nj)
      #pragma unroll
      for (int r = 0; r < 4; ++r){
        int row = mi*16 + lq*4 + r;
        int col = w*64 + nj*16 + lrow;
        obase[(size_t)row*2048 + col] = f2bf(acc[mi][nj][r]);
      }
}

extern "C" void kernel_launch(void* const* d_in, const int* in_sizes, int n_in,
                              void* d_out, int out_size, void* d_ws, size_t ws_size,
                              hipStream_t stream) {
  (void)in_sizes; (void)n_in; (void)out_size; (void)ws_size;
  const float* x     = (const float*)d_in[0];
  const float* ln1_w = (const float*)d_in[1];
  const float* ln1_b = (const float*)d_in[2];
  const float* Wq    = (const float*)d_in[3];
  const float* Wk    = (const float*)d_in[4];
  const float* Wv    = (const float*)d_in[5];
  const float* Wo    = (const float*)d_in[6];
  const float* ln2_w = (const float*)d_in[7];
  const float* ln2_b = (const float*)d_in[8];
  const float* W1    = (const float*)d_in[9];
  const float* b1    = (const float*)d_in[10];
  const float* W2    = (const float*)d_in[11];
  const float* b2    = (const float*)d_in[12];
  float* out = (float*)d_out;
  char* ws = (char*)d_ws;

  // ---- static arena, peak 172 MB (lifetime-aliased) ----
  const size_t MB = 1ull << 20;
  s16* Wqkv_t = (s16*)(ws + 0*MB);   // [0,8)  rows: 0-1023 q, 1024-2047 k, 2048-4095 v
  s16* Wo_t = (s16*)(ws + 8*MB);     // [8,12)
  s16* W1_t = (s16*)(ws + 12*MB);    // [12,20)
  s16* W2_t = (s16*)(ws + 20*MB);    // [20,28)
  s16* hbuf = (s16*)(ws + 28*MB);    // [28,44)  dead after QKV gemm
  s16* h2   = (s16*)(ws + 28*MB);    // [28,44)  alias dead hbuf (post-retention)
  s16* qkv  = (s16*)(ws + 44*MB);    // [44,108) [8192,4096] bf16, dead after ret_attn(b1)
  float* x1 = (float*)(ws + 44*MB);  // [44,76)  alias dead qkv head (post-retention)
  s16* fb   = (s16*)(ws + 76*MB);    // [76,140) alias dead qkv tail + US (FFN acts)
  s16* US   = (s16*)(ws + 108*MB);   // [108,140) bf16 per-batch U->S (in-place scan)
  s16* ob   = (s16*)(ws + 140*MB);   // [140,172)

  // weight transpose-convert (DK^-0.5 folded into Wq)
  conv_t<<<dim3(32,32),  256, 0, stream>>>(Wq, Wqkv_t, 1024, 1024, 0.08838834764831845f);
  conv_t<<<dim3(32,32),  256, 0, stream>>>(Wk, Wqkv_t + (size_t)1024*1024, 1024, 1024, 1.f);
  conv_t<<<dim3(64,32),  256, 0, stream>>>(Wv, Wqkv_t + (size_t)2048*1024, 1024, 2048, 1.f);
  conv_t<<<dim3(32,64),  256, 0, stream>>>(Wo, Wo_t, 2048, 1024, 1.f);
  conv_t<<<dim3(128,32), 256, 0, stream>>>(W1, W1_t, 1024, 4096, 1.f);
  conv_t<<<dim3(32,128), 256, 0, stream>>>(W2, W2_t, 4096, 1024, 1.f);

  ln_bf16<<<8192, 256, 0, stream>>>(x, ln1_w, ln1_b, hbuf);

  // fused QKV: [8192,4096] = hbuf @ Wqkv^T  (256^2 8-phase, 512 blocks, tiles_y=32)
  gemm256<<<512, 512, 0, stream>>>(hbuf, Wqkv_t, 4096, 1024, qkv, nullptr, 0, 32);

  for (int b = 0; b < 2; ++b){
    const s16* q_b = qkv + (size_t)b*4096*4096;
    const s16* k_b = q_b + 1024;
    const s16* v_b = q_b + 2048;
    s16* ob_b = ob + (size_t)b*4096*2048;
    ret_chunksum<<<512, 256, 0, stream>>>(k_b, v_b, US);
    ret_scan<<<128, 256, 0, stream>>>(US);
    ret_attn<<<512, 256, 0, stream>>>(q_b, k_b, v_b, US, ob_b);
  }

  // Wo: x1 = x + ob @ Wo^T   (64x128 tile, 1024 blocks, tiles_y = 128)
  gemm_nt_h<<<1024, 256, 0, stream>>>(ob, Wo_t, 8192, 1024, 2048, 2048, x1, nullptr, nullptr, x, 0, 128);
  ln_bf16<<<8192, 256, 0, stream>>>(x1, ln2_w, ln2_b, h2);

  // FFN: fb = gelu(h2 @ W1^T + b1)  [8192,4096]  (256^2 8-phase)
  gemm256<<<512, 512, 0, stream>>>(h2, W1_t, 4096, 1024, fb, b1, 1, 32);
  // out = x1 + b2 + fb @ W2^T   (64x128 tile, 1024 blocks, K=4096, tiles_y = 128)
  gemm_nt_h<<<1024, 256, 0, stream>>>(fb, W2_t, 8192, 1024, 4096, 4096, out, nullptr, b2, x1, 0, 128);
}

// Round 3
// 604.403 us; speedup vs baseline: 1.0309x; 1.0309x over previous
//
#include <hip/hip_runtime.h>
#include <math.h>

typedef short s16;
typedef __attribute__((ext_vector_type(8))) short short8;
typedef __attribute__((ext_vector_type(4))) float f32x4;

__device__ __forceinline__ float bf2f_lo(unsigned u){ return __builtin_bit_cast(float, u << 16); }
__device__ __forceinline__ float bf2f_hi(unsigned u){ return __builtin_bit_cast(float, u & 0xffff0000u); }
__device__ __forceinline__ float bf2f(unsigned short h){ return __builtin_bit_cast(float, (unsigned)h << 16); }
__device__ __forceinline__ s16 f2bf(float f){
  unsigned u = __builtin_bit_cast(unsigned, f);
  u += 0x7fffu + ((u >> 16) & 1u);
  return (s16)(u >> 16);
}
__device__ __forceinline__ void unpack8(int4 v, float* f){
  unsigned a=(unsigned)v.x, b=(unsigned)v.y, c=(unsigned)v.z, d=(unsigned)v.w;
  f[0]=bf2f_lo(a); f[1]=bf2f_hi(a); f[2]=bf2f_lo(b); f[3]=bf2f_hi(b);
  f[4]=bf2f_lo(c); f[5]=bf2f_hi(c); f[6]=bf2f_lo(d); f[7]=bf2f_hi(d);
}
// async global->LDS 16B: lds dest is wave-uniform base + lane*16
__device__ __forceinline__ void gl2lds16(const s16* g, s16* l){
  __builtin_amdgcn_global_load_lds((const __attribute__((address_space(1))) void*)g,
                                   (__attribute__((address_space(3))) void*)l, 16, 0, 0);
}

// ---------------- LayerNorm (fp32 in) -> bf16 out, D=1024, 1 block/row ------
__global__ __launch_bounds__(256) void ln_bf16(const float* __restrict__ x,
                                               const float* __restrict__ w,
                                               const float* __restrict__ b,
                                               s16* __restrict__ out){
  int row = blockIdx.x; int t = threadIdx.x;
  const float* xr = x + (size_t)row * 1024;
  float4 v = *(const float4*)(xr + t*4);
  float s = v.x + v.y + v.z + v.w;
  float ss = v.x*v.x + v.y*v.y + v.z*v.z + v.w*v.w;
  for (int o = 32; o > 0; o >>= 1){ s += __shfl_down(s, o, 64); ss += __shfl_down(ss, o, 64); }
  __shared__ float red[8];
  int wid = t >> 6, lane = t & 63;
  if (lane == 0){ red[wid] = s; red[4+wid] = ss; }
  __syncthreads();
  if (t == 0){
    float S = red[0]+red[1]+red[2]+red[3];
    float SS = red[4]+red[5]+red[6]+red[7];
    red[0] = S * (1.f/1024.f);
    red[1] = SS * (1.f/1024.f);
  }
  __syncthreads();
  float mu = red[0];
  float var = red[1] - mu*mu;
  float rstd = rsqrtf(var + 1e-6f);
  float vv[4] = {v.x, v.y, v.z, v.w};
  short4 o4;
  s16 tmp[4];
  #pragma unroll
  for (int i = 0; i < 4; ++i){
    int c = t*4 + i;
    float val = (vv[i] - mu) * rstd * w[c] + b[c];
    tmp[i] = f2bf(val);
  }
  o4.x = tmp[0]; o4.y = tmp[1]; o4.z = tmp[2]; o4.w = tmp[3];
  *(short4*)(out + (size_t)row*1024 + t*4) = o4;
}

// ---------------- transpose-convert fp32 W[K,N] -> bf16 Wt[N,K], with scale --
__global__ __launch_bounds__(256) void conv_t(const float* __restrict__ W,
                                              s16* __restrict__ Wt,
                                              int K, int N, float scale){
  __shared__ float tile[32][33];
  int n0 = blockIdx.x * 32, k0 = blockIdx.y * 32;
  int tx = threadIdx.x & 31, ty = threadIdx.x >> 5;   // ty 0..7
  #pragma unroll
  for (int i = 0; i < 4; ++i){
    int r = ty + i*8;
    tile[r][tx] = W[(size_t)(k0 + r)*N + n0 + tx];
  }
  __syncthreads();
  #pragma unroll
  for (int i = 0; i < 4; ++i){
    int r = ty + i*8;
    Wt[(size_t)(n0 + r)*K + k0 + tx] = f2bf(tile[tx][r] * scale);
  }
}

// XCD swizzle: 1D grid, tiles_y M-tiles (divisible by 8). Each XCD owns a
// disjoint M-row stripe (A fetched once, per-XCD L2); N iterated slowly so
// the B-slab stays hot across sy consecutive on-XCD blocks.
__device__ __forceinline__ void xcd_tile(int tiles_y, int& tx, int& ty){
  int id = blockIdx.x;
  int sy = tiles_y >> 3;
  int xcd = id & 7, p = id >> 3;
  ty = xcd * sy + (p % sy);
  tx = p / sy;
}

#define VMW(n) asm volatile("s_waitcnt vmcnt(" #n ")" ::: "memory")
#define BARR() asm volatile("s_barrier" ::: "memory")

// ============ 256x256 bf16 GEMM, m201 schedule (4 phases/tile, 1 vmcnt) =====
// C[M,N] = A[M,K] @ Bt[N,K]^T. 512 threads (8 waves 2Mx4N), 128KB LDS.
// Slots per buf: A0,A1,B0,B1 (128 rows x 64 each). Tile parity picks buf.
// Phase p of tile t: {ds-reads of quadrant; stage ONE half-tile; barrier;
// MFMA quadrant (16); barrier}. Staging: A1(t+1)@P1 -> nb.A1;
// A0(t+2)@P2 -> cb.A0 (freed at P1); B0(t+2)@P3 -> cb.B0 (freed at P1);
// B1(t+2)@P4 -> cb.B1 (freed at P2). Single vmcnt(6) at P4 retires ALL of
// tile t+1 (invariant: 6 outstanding at tile start, 14 before wait).
// Slot-recycle safety: a slot is restaged only >=1 full barrier after all
// waves' reads of it completed (reads land at lgkmcnt before the quadrant's
// MFMA, which precedes the phase-end barrier).
// LDS swizzle (both-sides): phys c8 = c8 ^ (row&7); writes via pre-swizzled
// GLOBAL source (gl2lds dest linear), reads XOR the addr.
__global__ __launch_bounds__(512,2) void gemm256(const s16* __restrict__ A,
                                                 const s16* __restrict__ Bt,
                                                 int N, int K,
                                                 s16* __restrict__ Cb,
                                                 const float* __restrict__ bias,
                                                 int flags, int tiles_y){
  __shared__ s16 lds[2*4*8192];   // [buf][slot: A0,A1,B0,B1][128*64]
  int t = threadIdx.x;
  int tx, ty; xcd_tile(tiles_y, tx, ty);
  int m0 = ty * 256, n0 = tx * 256;
  int w = t >> 6, lane = t & 63;
  int wm = w >> 2, wn = w & 3;         // 2M x 4N
  int lrow = lane & 15, lq = lane >> 4;
  int s = lrow & 7;

  // staging: thread i -> row (i>>3) of a 64-row round, col-group g (swizzled)
  int grow = t >> 3;                   // 0..63
  int g = (t & 7) ^ (grow & 7);
  const s16* Ag = A  + (size_t)(m0 + grow) * K + g*8;
  const s16* Bg = Bt + (size_t)(n0 + grow) * K + g*8;
  int wo = w * 512;                    // wave dest offset (elems) in 8KB round

  int abase = (wm*64 + lrow) * 64;
  int bbase = (wn*32 + lrow) * 64;
  int sw0 = ((lq ^ s) << 3);           // kk=0  -> c8 = lq
  int sw1 = (((4 + lq) ^ s) << 3);     // kk=32 -> c8 = 4+lq

  f32x4 acc[2][4][2][2];
  #pragma unroll
  for (int a = 0; a < 2; ++a)
    #pragma unroll
    for (int b = 0; b < 4; ++b)
      #pragma unroll
      for (int c = 0; c < 2; ++c)
        #pragma unroll
        for (int d = 0; d < 2; ++d) acc[a][b][c][d] = (f32x4){0.f,0.f,0.f,0.f};

  short8 af[2][4];        // [kk-slot][m], reloaded per mh
  short8 bfr[2][2][2];    // [nh][kk-slot][nj], both nh kept live

#define STG_A(buf,h,kt) do{ \
    gl2lds16(Ag + (size_t)((h)*128    )*K + (kt)*64, lds + ((buf)*4+(h))*8192 + wo); \
    gl2lds16(Ag + (size_t)((h)*128+ 64)*K + (kt)*64, lds + ((buf)*4+(h))*8192 + 4096 + wo); }while(0)
#define STG_B(buf,nh,kt) do{ \
    gl2lds16(Bg + (size_t)((nh)*128    )*K + (kt)*64, lds + ((buf)*4+2+(nh))*8192 + wo); \
    gl2lds16(Bg + (size_t)((nh)*128+ 64)*K + (kt)*64, lds + ((buf)*4+2+(nh))*8192 + 4096 + wo); }while(0)
#define RD_A(buf,mh) do{ const s16* p_ = lds + ((buf)*4+(mh))*8192 + abase; \
    _Pragma("unroll") for (int m_ = 0; m_ < 4; ++m_){ \
      af[0][m_] = *(const short8*)(p_ + m_*1024 + sw0); \
      af[1][m_] = *(const short8*)(p_ + m_*1024 + sw1); } }while(0)
#define RD_B(buf,nh) do{ const s16* p_ = lds + ((buf)*4+2+(nh))*8192 + bbase; \
    _Pragma("unroll") for (int n_ = 0; n_ < 2; ++n_){ \
      bfr[nh][0][n_] = *(const short8*)(p_ + n_*1024 + sw0); \
      bfr[nh][1][n_] = *(const short8*)(p_ + n_*1024 + sw1); } }while(0)
#define MFMA_Q(mh,nh) do{ __builtin_amdgcn_s_setprio(1); \
    _Pragma("unroll") for (int kk_ = 0; kk_ < 2; ++kk_) \
      _Pragma("unroll") for (int m_ = 0; m_ < 4; ++m_) \
        _Pragma("unroll") for (int n_ = 0; n_ < 2; ++n_) \
          acc[mh][m_][nh][n_] = __builtin_amdgcn_mfma_f32_16x16x32_bf16( \
              af[kk_][m_], bfr[nh][kk_][n_], acc[mh][m_][nh][n_], 0, 0, 0); \
    __builtin_amdgcn_s_setprio(0); }while(0)

  int NT = K >> 6;
  // prologue: all of tile0 + first 3 halves of tile1; retire tile0
  STG_A(0,0,0); STG_B(0,0,0); STG_B(0,1,0); STG_A(0,1,0);
  STG_A(1,0,1); STG_B(1,0,1); STG_B(1,1,1);
  VMW(6); BARR();

  for (int kt = 0; kt < NT-2; ++kt){
    int cb = kt & 1, nb = cb ^ 1;
    // P1 (mh0,nh0)
    RD_A(cb,0); RD_B(cb,0);
    STG_A(nb,1,kt+1);
    BARR(); MFMA_Q(0,0); BARR();
    // P2 (mh0,nh1)
    RD_B(cb,1);
    STG_A(cb,0,kt+2);
    BARR(); MFMA_Q(0,1); BARR();
    // P3 (mh1,nh0)
    RD_A(cb,1);
    STG_B(cb,0,kt+2);
    BARR(); MFMA_Q(1,0); BARR();
    // P4 (mh1,nh1)
    STG_B(cb,1,kt+2);
    VMW(6);
    BARR(); MFMA_Q(1,1); BARR();
  }
  { // tile NT-2: only A1(NT-1) left to stage; drain fully at P4
    int cb = (NT-2) & 1, nb = cb ^ 1;
    RD_A(cb,0); RD_B(cb,0);
    STG_A(nb,1,NT-1);
    BARR(); MFMA_Q(0,0); BARR();
    RD_B(cb,1);
    BARR(); MFMA_Q(0,1); BARR();
    RD_A(cb,1);
    BARR(); MFMA_Q(1,0); BARR();
    VMW(0);
    BARR(); MFMA_Q(1,1); BARR();
  }
  { // tile NT-1: pure compute
    int cb = (NT-1) & 1;
    RD_A(cb,0); RD_B(cb,0);
    BARR(); MFMA_Q(0,0); BARR();
    RD_B(cb,1);
    BARR(); MFMA_Q(0,1); BARR();
    RD_A(cb,1);
    BARR(); MFMA_Q(1,0); BARR();
    MFMA_Q(1,1);
  }
#undef STG_A
#undef STG_B
#undef RD_A
#undef RD_B
#undef MFMA_Q

  bool do_gelu = flags & 1;
  #pragma unroll
  for (int nh = 0; nh < 2; ++nh){
    #pragma unroll
    for (int nj = 0; nj < 2; ++nj){
      int col = n0 + wn*32 + nh*128 + nj*16 + lrow;
      float bcol = bias ? bias[col] : 0.f;
      #pragma unroll
      for (int mh = 0; mh < 2; ++mh){
        #pragma unroll
        for (int m = 0; m < 4; ++m){
          int row_base = m0 + wm*64 + mh*128 + m*16 + lq*4;
          #pragma unroll
          for (int r = 0; r < 4; ++r){
            float val = acc[mh][m][nh][nj][r] + bcol;
            if (do_gelu) val = 0.5f * val * (1.f + erff(val * 0.70710678118654752f));
            Cb[(size_t)(row_base + r) * N + col] = f2bf(val);
          }
        }
      }
    }
  }
}

// ============ 256x128 bf16 GEMM, same pipeline (2 phases/tile) ==============
// For N=1024 outputs (Wo, W2): grid = (N/128)*(M/256) = 256 blocks (1/CU).
// Slots per buf: A0,A1,B (128x64 each), 96KB LDS. 8 waves 2Mx4N, per-wave
// 128 rows (wm*64 + mh*128) x 32 cols (wn*32). Phase = one mh (16 MFMA).
// Staging: A1(t+1)@P1 -> nb.A1; A0(t+2),B(t+2)@P2 -> cb slots (freed at P1).
// Single vmcnt(4)@P2 retires tile t+1 (invariant: 4 outstanding at tile
// start, 10 before wait). fp32 or bf16 out, bias/gelu/resid fused.
__global__ __launch_bounds__(512,2) void gemm256h(const s16* __restrict__ A,
                                                  const s16* __restrict__ Bt,
                                                  int N, int K,
                                                  float* __restrict__ Cf,
                                                  s16* __restrict__ Cb,
                                                  const float* __restrict__ bias,
                                                  const float* __restrict__ resid,
                                                  int flags, int tiles_y){
  __shared__ s16 lds[2*3*8192];   // [buf][slot: A0,A1,B][128*64]
  int t = threadIdx.x;
  int tx, ty; xcd_tile(tiles_y, tx, ty);
  int m0 = ty * 256, n0 = tx * 128;
  int w = t >> 6, lane = t & 63;
  int wm = w >> 2, wn = w & 3;         // 2M x 4N
  int lrow = lane & 15, lq = lane >> 4;
  int s = lrow & 7;

  int grow = t >> 3;
  int g = (t & 7) ^ (grow & 7);
  const s16* Ag = A  + (size_t)(m0 + grow) * K + g*8;
  const s16* Bg = Bt + (size_t)(n0 + grow) * K + g*8;
  int wo = w * 512;

  int abase = (wm*64 + lrow) * 64;
  int bbase = (wn*32 + lrow) * 64;
  int sw0 = ((lq ^ s) << 3);
  int sw1 = (((4 + lq) ^ s) << 3);

  f32x4 acc[2][4][2];                  // [mh][m][nj]
  #pragma unroll
  for (int a = 0; a < 2; ++a)
    #pragma unroll
    for (int b = 0; b < 4; ++b)
      #pragma unroll
      for (int c = 0; c < 2; ++c) acc[a][b][c] = (f32x4){0.f,0.f,0.f,0.f};

  short8 af[2][4], bfr[2][2];          // [kk][m] / [kk][nj]

#define STG_A(buf,h,kt) do{ \
    gl2lds16(Ag + (size_t)((h)*128    )*K + (kt)*64, lds + ((buf)*3+(h))*8192 + wo); \
    gl2lds16(Ag + (size_t)((h)*128+ 64)*K + (kt)*64, lds + ((buf)*3+(h))*8192 + 4096 + wo); }while(0)
#define STG_B(buf,kt) do{ \
    gl2lds16(Bg + (size_t)0*K  + (kt)*64, lds + ((buf)*3+2)*8192 + wo); \
    gl2lds16(Bg + (size_t)64*K + (kt)*64, lds + ((buf)*3+2)*8192 + 4096 + wo); }while(0)
#define RD_A(buf,mh) do{ const s16* p_ = lds + ((buf)*3+(mh))*8192 + abase; \
    _Pragma("unroll") for (int m_ = 0; m_ < 4; ++m_){ \
      af[0][m_] = *(const short8*)(p_ + m_*1024 + sw0); \
      af[1][m_] = *(const short8*)(p_ + m_*1024 + sw1); } }while(0)
#define RD_B(buf) do{ const s16* p_ = lds + ((buf)*3+2)*8192 + bbase; \
    _Pragma("unroll") for (int n_ = 0; n_ < 2; ++n_){ \
      bfr[0][n_] = *(const short8*)(p_ + n_*1024 + sw0); \
      bfr[1][n_] = *(const short8*)(p_ + n_*1024 + sw1); } }while(0)
#define MFMA_H(mh) do{ __builtin_amdgcn_s_setprio(1); \
    _Pragma("unroll") for (int kk_ = 0; kk_ < 2; ++kk_) \
      _Pragma("unroll") for (int m_ = 0; m_ < 4; ++m_) \
        _Pragma("unroll") for (int n_ = 0; n_ < 2; ++n_) \
          acc[mh][m_][n_] = __builtin_amdgcn_mfma_f32_16x16x32_bf16( \
              af[kk_][m_], bfr[kk_][n_], acc[mh][m_][n_], 0, 0, 0); \
    __builtin_amdgcn_s_setprio(0); }while(0)

  int NT = K >> 6;
  // prologue: tile0 (A0,B,A1) + tile1 (A0,B); retire tile0
  STG_A(0,0,0); STG_B(0,0); STG_A(0,1,0);
  STG_A(1,0,1); STG_B(1,1);
  VMW(4); BARR();

  for (int kt = 0; kt < NT-2; ++kt){
    int cb = kt & 1, nb = cb ^ 1;
    // P1 (mh0)
    RD_A(cb,0); RD_B(cb);
    STG_A(nb,1,kt+1);
    BARR(); MFMA_H(0); BARR();
    // P2 (mh1)
    RD_A(cb,1);
    STG_A(cb,0,kt+2); STG_B(cb,kt+2);
    VMW(4);
    BARR(); MFMA_H(1); BARR();
  }
  { // tile NT-2
    int cb = (NT-2) & 1, nb = cb ^ 1;
    RD_A(cb,0); RD_B(cb);
    STG_A(nb,1,NT-1);
    BARR(); MFMA_H(0); BARR();
    RD_A(cb,1);
    VMW(0);
    BARR(); MFMA_H(1); BARR();
  }
  { // tile NT-1
    int cb = (NT-1) & 1;
    RD_A(cb,0); RD_B(cb);
    BARR(); MFMA_H(0); BARR();
    RD_A(cb,1);
    MFMA_H(1);
  }
#undef STG_A
#undef STG_B
#undef RD_A
#undef RD_B
#undef MFMA_H

  bool do_gelu = flags & 1;
  bool out_bf = flags & 2;
  #pragma unroll
  for (int nj = 0; nj < 2; ++nj){
    int col = n0 + wn*32 + nj*16 + lrow;
    float bcol = bias ? bias[col] : 0.f;
    #pragma unroll
    for (int mh = 0; mh < 2; ++mh){
      #pragma unroll
      for (int m = 0; m < 4; ++m){
        int row_base = m0 + wm*64 + mh*128 + m*16 + lq*4;
        #pragma unroll
        for (int r = 0; r < 4; ++r){
          int grow_ = row_base + r;
          float val = acc[mh][m][nj][r] + bcol;
          if (do_gelu) val = 0.5f * val * (1.f + erff(val * 0.70710678118654752f));
          if (resid) val += resid[(size_t)grow_ * N + col];
          if (out_bf) Cb[(size_t)grow_ * N + col] = f2bf(val);
          else        Cf[(size_t)grow_ * N + col] = val;
        }
      }
    }
  }
}

// ---------------- retention 2a (per batch): U_t[dv][dk] = (d_k*k (x) v)^T ----
// grid 512 = h(8) + n(64); k,v from fused qkv (row stride 4096)
__global__ __launch_bounds__(256,2) void ret_chunksum(const s16* __restrict__ k,
                                                      const s16* __restrict__ v,
                                                      s16* __restrict__ U){
  int bi = blockIdx.x;
  int h = bi & 7, n = bi >> 3;
  int t = threadIdx.x;
  __shared__ s16 ks[128*72];   // ks[dk][s], d_k decay folded
  __shared__ s16 vs[256*72];   // vs[dv][s]
  float log2b = log2f(1.f - exp2f(-5.f - (float)h));
  const s16* kbase = k + (size_t)(n*64)*4096 + h*128;
  const s16* vbase = v + (size_t)(n*64)*4096 + h*256;
  #pragma unroll
  for (int i = 0; i < 4; ++i){
    int e = i*2048 + t*8;
    int s = e >> 7, dk = e & 127;
    int4 kv = *(const int4*)(kbase + (size_t)s*4096 + dk);
    float f[8]; unpack8(kv, f);
    float dec = exp2f(log2b * (float)(63 - s));
    #pragma unroll
    for (int j = 0; j < 8; ++j) ks[(dk+j)*72 + s] = f2bf(f[j]*dec);
  }
  #pragma unroll
  for (int i = 0; i < 8; ++i){
    int e = i*2048 + t*8;
    int s = e >> 8, dv = e & 255;
    int4 vv = *(const int4*)(vbase + (size_t)s*4096 + dv);
    s16 tmp[8]; *(int4*)tmp = vv;
    #pragma unroll
    for (int j = 0; j < 8; ++j) vs[(dv+j)*72 + s] = tmp[j];
  }
  __syncthreads();
  int w = t >> 6, lane = t & 63;
  int m0w = w*64;   // dv rows, 4 tiles per wave
  int lrow = lane & 15, lq = lane >> 4;
  f32x4 acc[4][8];
  #pragma unroll
  for (int mi = 0; mi < 4; ++mi)
    #pragma unroll
    for (int ni = 0; ni < 8; ++ni) acc[mi][ni] = (f32x4){0.f,0.f,0.f,0.f};
  #pragma unroll
  for (int kk = 0; kk < 64; kk += 32){
    short8 af[4], bfr[8];
    #pragma unroll
    for (int mi = 0; mi < 4; ++mi)
      af[mi] = *(short8*)&vs[(m0w + mi*16 + lrow)*72 + kk + lq*8];
    #pragma unroll
    for (int ni = 0; ni < 8; ++ni)
      bfr[ni] = *(short8*)&ks[(ni*16 + lrow)*72 + kk + lq*8];
    #pragma unroll
    for (int mi = 0; mi < 4; ++mi)
      #pragma unroll
      for (int ni = 0; ni < 8; ++ni)
        acc[mi][ni] = __builtin_amdgcn_mfma_f32_16x16x32_bf16(af[mi], bfr[ni], acc[mi][ni], 0, 0, 0);
  }
  s16* Ub = U + ((size_t)(h*64 + n))*32768;
  #pragma unroll
  for (int mi = 0; mi < 4; ++mi)
    #pragma unroll
    for (int ni = 0; ni < 8; ++ni)
      #pragma unroll
      for (int r = 0; r < 4; ++r){
        int row = m0w + mi*16 + lq*4 + r;   // dv
        int col = ni*16 + lrow;             // dk
        Ub[(size_t)row*128 + col] = f2bf(acc[mi][ni][r]);
      }
}

// ---------------- retention 2b (per batch): in-place decay prefix scan -------
__global__ __launch_bounds__(256) void ret_scan(s16* __restrict__ US){
  int tid = blockIdx.x*256 + threadIdx.x;       // 32768 threads
  int h = tid >> 12;
  int rem = tid & 4095;
  int dv = rem >> 4, dk0 = (rem & 15)*8;
  float log2b = log2f(1.f - exp2f(-5.f - (float)h));
  float dc = exp2f(log2b * 64.f);
  s16* base = US + (size_t)h*64*32768 + (size_t)dv*128 + dk0;
  float acc[8] = {0.f,0.f,0.f,0.f,0.f,0.f,0.f,0.f};
  #pragma unroll 4
  for (int n = 0; n < 64; ++n){
    s16* p = base + (size_t)n*32768;
    int4 u4 = *(const int4*)p;
    float uf[8]; unpack8(u4, uf);
    s16 sb[8];
    #pragma unroll
    for (int j = 0; j < 8; ++j) sb[j] = f2bf(acc[j]);
    *(int4*)p = *(int4*)sb;
    #pragma unroll
    for (int j = 0; j < 8; ++j) acc[j] = acc[j]*dc + uf[j];
  }
}

// ---------------- retention fused (per batch): O = mask(qk^T)@v + dq*(q@S) ---
// grid 512 = h(8) + n(64). q,k,v from fused qkv (stride 4096); S_t [h][n][256][128]
__global__ __launch_bounds__(256,2) void ret_attn(const s16* __restrict__ q,
                                                  const s16* __restrict__ k,
                                                  const s16* __restrict__ v,
                                                  const s16* __restrict__ S,
                                                  s16* __restrict__ o){
  int bi = blockIdx.x;
  int h = bi & 7, n = bi >> 3;
  int t = threadIdx.x;
  int w = t >> 6, lane = t & 63;
  int lrow = lane & 15, lq = lane >> 4;
  float log2b = log2f(1.f - exp2f(-5.f - (float)h));
  __shared__ s16 As[64*72];    // masked scores, A-operand staging
  __shared__ s16 vs[256*72];   // v^T [dv][s]

  // stage v transposed
  const s16* vbase = v + (size_t)(n*64)*4096 + h*256;
  #pragma unroll
  for (int i = 0; i < 8; ++i){
    int e = i*2048 + t*8;
    int s = e >> 8, dv = e & 255;
    int4 vv = *(const int4*)(vbase + (size_t)s*4096 + dv);
    s16 tmp[8]; *(int4*)tmp = vv;
    #pragma unroll
    for (int j = 0; j < 8; ++j) vs[(dv+j)*72 + s] = tmp[j];
  }

  // phase 1: wave w computes A[:, 16w:16w+16] = q @ k^T, masked
  const s16* qbase = q + (size_t)(n*64)*4096 + h*128;
  const s16* kbase = k + (size_t)(n*64)*4096 + h*128;
  short8 qf[4][4];   // [row-tile][kstep], reused in phase 2
  #pragma unroll
  for (int ti = 0; ti < 4; ++ti)
    #pragma unroll
    for (int c = 0; c < 4; ++c)
      qf[ti][c] = *(const short8*)(qbase + (size_t)(ti*16 + lrow)*4096 + c*32 + lq*8);
  short8 kf[4];
  #pragma unroll
  for (int c = 0; c < 4; ++c)
    kf[c] = *(const short8*)(kbase + (size_t)(16*w + lrow)*4096 + c*32 + lq*8);
  #pragma unroll
  for (int ti = 0; ti < 4; ++ti){
    f32x4 acc_a = (f32x4){0.f,0.f,0.f,0.f};
    #pragma unroll
    for (int c = 0; c < 4; ++c)
      acc_a = __builtin_amdgcn_mfma_f32_16x16x32_bf16(qf[ti][c], kf[c], acc_a, 0, 0, 0);
    #pragma unroll
    for (int r = 0; r < 4; ++r){
      int ti_idx = ti*16 + lq*4 + r;
      int s_idx = 16*w + lrow;
      int d = ti_idx - s_idx;
      float val = (d >= 0) ? acc_a[r] * exp2f(log2b * (float)d) : 0.f;
      As[ti_idx*72 + s_idx] = f2bf(val);
    }
  }
  __syncthreads();

  // phase 2: wave w owns dv cols [64w, 64w+64)
  f32x4 acc[4][4];
  #pragma unroll
  for (int mi = 0; mi < 4; ++mi)
    #pragma unroll
    for (int nj = 0; nj < 4; ++nj) acc[mi][nj] = (f32x4){0.f,0.f,0.f,0.f};

  // q @ S  (K = 128)
  const s16* Sbase = S + ((size_t)(h*64 + n)*256 + w*64)*128;
  #pragma unroll
  for (int c = 0; c < 4; ++c){
    short8 bf[4];
    #pragma unroll
    for (int nj = 0; nj < 4; ++nj)
      bf[nj] = *(const short8*)(Sbase + (size_t)(nj*16 + lrow)*128 + c*32 + lq*8);
    #pragma unroll
    for (int mi = 0; mi < 4; ++mi)
      #pragma unroll
      for (int nj = 0; nj < 4; ++nj)
        acc[mi][nj] = __builtin_amdgcn_mfma_f32_16x16x32_bf16(qf[mi][c], bf[nj], acc[mi][nj], 0, 0, 0);
  }
  // scale by d_q = b^(row+1)
  #pragma unroll
  for (int mi = 0; mi < 4; ++mi){
    #pragma unroll
    for (int r = 0; r < 4; ++r){
      float dq = exp2f(log2b * (float)(mi*16 + lq*4 + r + 1));
      #pragma unroll
      for (int nj = 0; nj < 4; ++nj) acc[mi][nj][r] *= dq;
    }
  }
  // A @ v  (K = 64)
  #pragma unroll
  for (int c = 0; c < 2; ++c){
    short8 af[4], bf[4];
    #pragma unroll
    for (int mi = 0; mi < 4; ++mi)
      af[mi] = *(short8*)&As[(mi*16 + lrow)*72 + c*32 + lq*8];
    #pragma unroll
    for (int nj = 0; nj < 4; ++nj)
      bf[nj] = *(short8*)&vs[(w*64 + nj*16 + lrow)*72 + c*32 + lq*8];
    #pragma unroll
    for (int mi = 0; mi < 4; ++mi)
      #pragma unroll
      for (int nj = 0; nj < 4; ++nj)
        acc[mi][nj] = __builtin_amdgcn_mfma_f32_16x16x32_bf16(af[mi], bf[nj], acc[mi][nj], 0, 0, 0);
  }
  // write O
  s16* obase = o + (size_t)(n*64)*2048 + h*256;
  #pragma unroll
  for (int mi = 0; mi < 4; ++mi)
    #pragma unroll
    for (int nj = 0; nj < 4; ++nj)
      #pragma unroll
      for (int r = 0; r < 4; ++r){
        int row = mi*16 + lq*4 + r;
        int col = w*64 + nj*16 + lrow;
        obase[(size_t)row*2048 + col] = f2bf(acc[mi][nj][r]);
      }
}

extern "C" void kernel_launch(void* const* d_in, const int* in_sizes, int n_in,
                              void* d_out, int out_size, void* d_ws, size_t ws_size,
                              hipStream_t stream) {
  (void)in_sizes; (void)n_in; (void)out_size; (void)ws_size;
  const float* x     = (const float*)d_in[0];
  const float* ln1_w = (const float*)d_in[1];
  const float* ln1_b = (const float*)d_in[2];
  const float* Wq    = (const float*)d_in[3];
  const float* Wk    = (const float*)d_in[4];
  const float* Wv    = (const float*)d_in[5];
  const float* Wo    = (const float*)d_in[6];
  const float* ln2_w = (const float*)d_in[7];
  const float* ln2_b = (const float*)d_in[8];
  const float* W1    = (const float*)d_in[9];
  const float* b1    = (const float*)d_in[10];
  const float* W2    = (const float*)d_in[11];
  const float* b2    = (const float*)d_in[12];
  float* out = (float*)d_out;
  char* ws = (char*)d_ws;

  // ---- static arena, peak 172 MB (lifetime-aliased) ----
  const size_t MB = 1ull << 20;
  s16* Wqkv_t = (s16*)(ws + 0*MB);   // [0,8)  rows: 0-1023 q, 1024-2047 k, 2048-4095 v
  s16* Wo_t = (s16*)(ws + 8*MB);     // [8,12)
  s16* W1_t = (s16*)(ws + 12*MB);    // [12,20)
  s16* W2_t = (s16*)(ws + 20*MB);    // [20,28)
  s16* hbuf = (s16*)(ws + 28*MB);    // [28,44)  dead after QKV gemm
  s16* h2   = (s16*)(ws + 28*MB);    // [28,44)  alias dead hbuf (post-retention)
  s16* qkv  = (s16*)(ws + 44*MB);    // [44,108) [8192,4096] bf16, dead after ret_attn(b1)
  float* x1 = (float*)(ws + 44*MB);  // [44,76)  alias dead qkv head (post-retention)
  s16* fb   = (s16*)(ws + 76*MB);    // [76,140) alias dead qkv tail + US (FFN acts)
  s16* US   = (s16*)(ws + 108*MB);   // [108,140) bf16 per-batch U->S (in-place scan)
  s16* ob   = (s16*)(ws + 140*MB);   // [140,172)

  // weight transpose-convert (DK^-0.5 folded into Wq)
  conv_t<<<dim3(32,32),  256, 0, stream>>>(Wq, Wqkv_t, 1024, 1024, 0.08838834764831845f);
  conv_t<<<dim3(32,32),  256, 0, stream>>>(Wk, Wqkv_t + (size_t)1024*1024, 1024, 1024, 1.f);
  conv_t<<<dim3(64,32),  256, 0, stream>>>(Wv, Wqkv_t + (size_t)2048*1024, 1024, 2048, 1.f);
  conv_t<<<dim3(32,64),  256, 0, stream>>>(Wo, Wo_t, 2048, 1024, 1.f);
  conv_t<<<dim3(128,32), 256, 0, stream>>>(W1, W1_t, 1024, 4096, 1.f);
  conv_t<<<dim3(32,128), 256, 0, stream>>>(W2, W2_t, 4096, 1024, 1.f);

  ln_bf16<<<8192, 256, 0, stream>>>(x, ln1_w, ln1_b, hbuf);

  // fused QKV: [8192,4096] = hbuf @ Wqkv^T  (256^2 pipelined, 512 blocks)
  gemm256<<<512, 512, 0, stream>>>(hbuf, Wqkv_t, 4096, 1024, qkv, nullptr, 0, 32);

  for (int b = 0; b < 2; ++b){
    const s16* q_b = qkv + (size_t)b*4096*4096;
    const s16* k_b = q_b + 1024;
    const s16* v_b = q_b + 2048;
    s16* ob_b = ob + (size_t)b*4096*2048;
    ret_chunksum<<<512, 256, 0, stream>>>(k_b, v_b, US);
    ret_scan<<<128, 256, 0, stream>>>(US);
    ret_attn<<<512, 256, 0, stream>>>(q_b, k_b, v_b, US, ob_b);
  }

  // Wo: x1 = x + ob @ Wo^T   (256x128 pipelined, 256 blocks, tiles_y=32)
  gemm256h<<<256, 512, 0, stream>>>(ob, Wo_t, 1024, 2048, x1, nullptr, nullptr, x, 0, 32);
  ln_bf16<<<8192, 256, 0, stream>>>(x1, ln2_w, ln2_b, h2);

  // FFN: fb = gelu(h2 @ W1^T + b1)  [8192,4096]  (256^2 pipelined)
  gemm256<<<512, 512, 0, stream>>>(h2, W1_t, 4096, 1024, fb, b1, 1, 32);
  // out = x1 + b2 + fb @ W2^T   (256x128 pipelined, 256 blocks, K=4096)
  gemm256h<<<256, 512, 0, stream>>>(fb, W2_t, 1024, 4096, out, nullptr, b2, x1, 0, 32);
}

// Round 4
// 604.192 us; speedup vs baseline: 1.0313x; 1.0003x over previous
//
#include <hip/hip_runtime.h>
#include <math.h>

typedef short s16;
typedef __attribute__((ext_vector_type(8))) short short8;
typedef __attribute__((ext_vector_type(4))) float f32x4;

__device__ __forceinline__ float bf2f_lo(unsigned u){ return __builtin_bit_cast(float, u << 16); }
__device__ __forceinline__ float bf2f_hi(unsigned u){ return __builtin_bit_cast(float, u & 0xffff0000u); }
__device__ __forceinline__ float bf2f(unsigned short h){ return __builtin_bit_cast(float, (unsigned)h << 16); }
__device__ __forceinline__ s16 f2bf(float f){
  unsigned u = __builtin_bit_cast(unsigned, f);
  u += 0x7fffu + ((u >> 16) & 1u);
  return (s16)(u >> 16);
}
__device__ __forceinline__ void unpack8(int4 v, float* f){
  unsigned a=(unsigned)v.x, b=(unsigned)v.y, c=(unsigned)v.z, d=(unsigned)v.w;
  f[0]=bf2f_lo(a); f[1]=bf2f_hi(a); f[2]=bf2f_lo(b); f[3]=bf2f_hi(b);
  f[4]=bf2f_lo(c); f[5]=bf2f_hi(c); f[6]=bf2f_lo(d); f[7]=bf2f_hi(d);
}
// async global->LDS 16B: lds dest is wave-uniform base + lane*16
__device__ __forceinline__ void gl2lds16(const s16* g, s16* l){
  __builtin_amdgcn_global_load_lds((const __attribute__((address_space(1))) void*)g,
                                   (__attribute__((address_space(3))) void*)l, 16, 0, 0);
}

// ---------------- LayerNorm (fp32 in) -> bf16 out, D=1024, 1 block/row ------
__global__ __launch_bounds__(256) void ln_bf16(const float* __restrict__ x,
                                               const float* __restrict__ w,
                                               const float* __restrict__ b,
                                               s16* __restrict__ out){
  int row = blockIdx.x; int t = threadIdx.x;
  const float* xr = x + (size_t)row * 1024;
  float4 v = *(const float4*)(xr + t*4);
  float s = v.x + v.y + v.z + v.w;
  float ss = v.x*v.x + v.y*v.y + v.z*v.z + v.w*v.w;
  for (int o = 32; o > 0; o >>= 1){ s += __shfl_down(s, o, 64); ss += __shfl_down(ss, o, 64); }
  __shared__ float red[8];
  int wid = t >> 6, lane = t & 63;
  if (lane == 0){ red[wid] = s; red[4+wid] = ss; }
  __syncthreads();
  if (t == 0){
    float S = red[0]+red[1]+red[2]+red[3];
    float SS = red[4]+red[5]+red[6]+red[7];
    red[0] = S * (1.f/1024.f);
    red[1] = SS * (1.f/1024.f);
  }
  __syncthreads();
  float mu = red[0];
  float var = red[1] - mu*mu;
  float rstd = rsqrtf(var + 1e-6f);
  float vv[4] = {v.x, v.y, v.z, v.w};
  short4 o4;
  s16 tmp[4];
  #pragma unroll
  for (int i = 0; i < 4; ++i){
    int c = t*4 + i;
    float val = (vv[i] - mu) * rstd * w[c] + b[c];
    tmp[i] = f2bf(val);
  }
  o4.x = tmp[0]; o4.y = tmp[1]; o4.z = tmp[2]; o4.w = tmp[3];
  *(short4*)(out + (size_t)row*1024 + t*4) = o4;
}

// ---------------- transpose-convert fp32 W[K,N] -> bf16 Wt[N,K], with scale --
__global__ __launch_bounds__(256) void conv_t(const float* __restrict__ W,
                                              s16* __restrict__ Wt,
                                              int K, int N, float scale){
  __shared__ float tile[32][33];
  int n0 = blockIdx.x * 32, k0 = blockIdx.y * 32;
  int tx = threadIdx.x & 31, ty = threadIdx.x >> 5;   // ty 0..7
  #pragma unroll
  for (int i = 0; i < 4; ++i){
    int r = ty + i*8;
    tile[r][tx] = W[(size_t)(k0 + r)*N + n0 + tx];
  }
  __syncthreads();
  #pragma unroll
  for (int i = 0; i < 4; ++i){
    int r = ty + i*8;
    Wt[(size_t)(n0 + r)*K + k0 + tx] = f2bf(tile[tx][r] * scale);
  }
}

// XCD swizzle: 1D grid, tiles_y M-tiles (divisible by 8). Each XCD owns a
// disjoint M-row stripe (A fetched once, per-XCD L2); N iterated slowly so
// the B-slab stays hot across sy consecutive on-XCD blocks.
__device__ __forceinline__ void xcd_tile(int tiles_y, int& tx, int& ty){
  int id = blockIdx.x;
  int sy = tiles_y >> 3;
  int xcd = id & 7, p = id >> 3;
  ty = xcd * sy + (p % sy);
  tx = p / sy;
}

#define VMW(n) asm volatile("s_waitcnt vmcnt(" #n ")" ::: "memory")
#define BARR() asm volatile("s_barrier" ::: "memory")

// ============ 256x256 bf16 GEMM, shifted reg-pipeline (4 phases/tile) =======
// C[M,N] = A[M,K] @ Bt[N,K]^T. 512 threads (8 waves 2Mx4N), 128KB LDS.
// Phase layout: {STG; [VMW]; BARR; RD(frags for NEXT phase); MFMA(this phase)}
// -> ds_read burst of phase p+1 overlaps MFMA(p); MFMA(p)'s operands were
// read during p-1 and retire under p-1's MFMA (fine-grained lgkm).
// Frag regs (static, no parity): afA=A0, afB=A1, bf0=B0, bf1=B1.
//   P1: MFMA(0,0){afA,bf0}, RD bf1<-cb.B1,  STG A1(t+1)->nb.A1
//   P2: MFMA(0,1){afA,bf1}, RD afB<-cb.A1,  STG A0(t+2)->cb.A0
//   P3: MFMA(1,0){afB,bf0},                 STG B0(t+2)->cb.B0
//   P4: MFMA(1,1){afB,bf1}, RD afA<-nb.A0,bf0<-nb.B0, STG B1(t+2)->cb.B1, VMW(6)
// vmcnt invariant: 6 outstanding at tile start, +8/tile, VMW(6)@P4 retires
// exactly tile t+1 (8 loads). Slot-recycle: every restage is >=1 barrier +
// one MFMA region + ~200cy gl2lds-write latency after the slot's last read.
// LDS swizzle (both-sides): phys c8 = c8 ^ (row&7); writes via pre-swizzled
// GLOBAL source (gl2lds dest linear), reads XOR the addr. (0 conflicts, r3)
__global__ __launch_bounds__(512,2) void gemm256(const s16* __restrict__ A,
                                                 const s16* __restrict__ Bt,
                                                 int N, int K,
                                                 s16* __restrict__ Cb,
                                                 const float* __restrict__ bias,
                                                 int flags, int tiles_y){
  __shared__ s16 lds[2*4*8192];   // [buf][slot: A0,A1,B0,B1][128*64]
  int t = threadIdx.x;
  int tx, ty; xcd_tile(tiles_y, tx, ty);
  int m0 = ty * 256, n0 = tx * 256;
  int w = t >> 6, lane = t & 63;
  int wm = w >> 2, wn = w & 3;         // 2M x 4N
  int lrow = lane & 15, lq = lane >> 4;
  int s = lrow & 7;

  // staging: thread i -> row (i>>3) of a 64-row round, col-group g (swizzled)
  int grow = t >> 3;                   // 0..63
  int g = (t & 7) ^ (grow & 7);
  const s16* Ag = A  + (size_t)(m0 + grow) * K + g*8;
  const s16* Bg = Bt + (size_t)(n0 + grow) * K + g*8;
  int wo = w * 512;                    // wave dest offset (elems) in 8KB round

  int abase = (wm*64 + lrow) * 64;
  int bbase = (wn*32 + lrow) * 64;
  int sw0 = ((lq ^ s) << 3);           // kk=0  -> c8 = lq
  int sw1 = (((4 + lq) ^ s) << 3);     // kk=32 -> c8 = 4+lq

  f32x4 acc[2][4][2][2];
  #pragma unroll
  for (int a = 0; a < 2; ++a)
    #pragma unroll
    for (int b = 0; b < 4; ++b)
      #pragma unroll
      for (int c = 0; c < 2; ++c)
        #pragma unroll
        for (int d = 0; d < 2; ++d) acc[a][b][c][d] = (f32x4){0.f,0.f,0.f,0.f};

  short8 afA[2][4], afB[2][4];         // A0-half frags / A1-half frags
  short8 bf0[2][2], bf1[2][2];         // B0 / B1 frags

#define STG_A(buf,h,kt) do{ \
    gl2lds16(Ag + (size_t)((h)*128    )*K + (kt)*64, lds + ((buf)*4+(h))*8192 + wo); \
    gl2lds16(Ag + (size_t)((h)*128+ 64)*K + (kt)*64, lds + ((buf)*4+(h))*8192 + 4096 + wo); }while(0)
#define STG_B(buf,nh,kt) do{ \
    gl2lds16(Bg + (size_t)((nh)*128    )*K + (kt)*64, lds + ((buf)*4+2+(nh))*8192 + wo); \
    gl2lds16(Bg + (size_t)((nh)*128+ 64)*K + (kt)*64, lds + ((buf)*4+2+(nh))*8192 + 4096 + wo); }while(0)
#define RD_AF(buf,mh,dst) do{ const s16* p_ = lds + ((buf)*4+(mh))*8192 + abase; \
    _Pragma("unroll") for (int m_ = 0; m_ < 4; ++m_){ \
      dst[0][m_] = *(const short8*)(p_ + m_*1024 + sw0); \
      dst[1][m_] = *(const short8*)(p_ + m_*1024 + sw1); } }while(0)
#define RD_BF(buf,nh,dst) do{ const s16* p_ = lds + ((buf)*4+2+(nh))*8192 + bbase; \
    _Pragma("unroll") for (int n_ = 0; n_ < 2; ++n_){ \
      dst[0][n_] = *(const short8*)(p_ + n_*1024 + sw0); \
      dst[1][n_] = *(const short8*)(p_ + n_*1024 + sw1); } }while(0)
#define MFMA_Q(mh,nh,A_,B_) do{ __builtin_amdgcn_s_setprio(1); \
    _Pragma("unroll") for (int kk_ = 0; kk_ < 2; ++kk_) \
      _Pragma("unroll") for (int m_ = 0; m_ < 4; ++m_) \
        _Pragma("unroll") for (int n_ = 0; n_ < 2; ++n_) \
          acc[mh][m_][nh][n_] = __builtin_amdgcn_mfma_f32_16x16x32_bf16( \
              A_[kk_][m_], B_[kk_][n_], acc[mh][m_][nh][n_], 0, 0, 0); \
    __builtin_amdgcn_s_setprio(0); }while(0)

  int NT = K >> 6;
  // prologue: tile0 fully + {A0,B0,B1}(1); retire tile0; preload P1 frags
  STG_A(0,0,0); STG_B(0,0,0); STG_B(0,1,0); STG_A(0,1,0);
  STG_A(1,0,1); STG_B(1,0,1); STG_B(1,1,1);
  VMW(6); BARR();
  RD_AF(0,0,afA); RD_BF(0,0,bf0);

  for (int kt = 0; kt < NT-2; ++kt){
    int cb = kt & 1, nb = cb ^ 1;
    // P1
    STG_A(nb,1,kt+1);
    BARR();
    RD_BF(cb,1,bf1);
    MFMA_Q(0,0,afA,bf0);
    // P2
    STG_A(cb,0,kt+2);
    BARR();
    RD_AF(cb,1,afB);
    MFMA_Q(0,1,afA,bf1);
    // P3
    STG_B(cb,0,kt+2);
    BARR();
    MFMA_Q(1,0,afB,bf0);
    // P4
    STG_B(cb,1,kt+2);
    VMW(6);
    BARR();
    RD_AF(nb,0,afA); RD_BF(nb,0,bf0);
    MFMA_Q(1,1,afB,bf1);
  }
  { // tile NT-2: stage only A1(NT-1); full drain at P4
    int cb = (NT-2) & 1, nb = cb ^ 1;
    STG_A(nb,1,NT-1);
    BARR(); RD_BF(cb,1,bf1); MFMA_Q(0,0,afA,bf0);
    BARR(); RD_AF(cb,1,afB); MFMA_Q(0,1,afA,bf1);
    BARR(); MFMA_Q(1,0,afB,bf0);
    VMW(0);
    BARR();
    RD_AF(nb,0,afA); RD_BF(nb,0,bf0);
    MFMA_Q(1,1,afB,bf1);
  }
  { // tile NT-1: pure compute
    int cb = (NT-1) & 1;
    BARR(); RD_BF(cb,1,bf1); MFMA_Q(0,0,afA,bf0);
    BARR(); RD_AF(cb,1,afB); MFMA_Q(0,1,afA,bf1);
    BARR(); MFMA_Q(1,0,afB,bf0);
    MFMA_Q(1,1,afB,bf1);
  }
#undef STG_A
#undef STG_B
#undef RD_AF
#undef RD_BF
#undef MFMA_Q

  bool do_gelu = flags & 1;
  #pragma unroll
  for (int nh = 0; nh < 2; ++nh){
    #pragma unroll
    for (int nj = 0; nj < 2; ++nj){
      int col = n0 + wn*32 + nh*128 + nj*16 + lrow;
      float bcol = bias ? bias[col] : 0.f;
      #pragma unroll
      for (int mh = 0; mh < 2; ++mh){
        #pragma unroll
        for (int m = 0; m < 4; ++m){
          int row_base = m0 + wm*64 + mh*128 + m*16 + lq*4;
          #pragma unroll
          for (int r = 0; r < 4; ++r){
            float val = acc[mh][m][nh][nj][r] + bcol;
            if (do_gelu) val = 0.5f * val * (1.f + erff(val * 0.70710678118654752f));
            Cb[(size_t)(row_base + r) * N + col] = f2bf(val);
          }
        }
      }
    }
  }
}

// ============ 256x128 bf16 GEMM, shifted reg-pipeline (2 phases/tile) =======
// N=1024 outputs (Wo, W2): grid = (N/128)*(M/256) = 256 blocks (1/CU), 96KB.
// P1: MFMA0{afA,bfCUR}, RD afB<-cb.A1, STG A1(t+1)->nb.A1
// P2: MFMA1{afB,bfCUR}, RD afA<-nb.A0, bfNXT<-nb.B, STG {A0,B}(t+2)->cb, VMW(4)
// bf parity handled by 2-tile unroll (static regs). vmcnt: 4 at tile start,
// +2+4/tile, VMW(4)@P2 retires tile t+1 (6 loads).
__global__ __launch_bounds__(512,2) void gemm256h(const s16* __restrict__ A,
                                                  const s16* __restrict__ Bt,
                                                  int N, int K,
                                                  float* __restrict__ Cf,
                                                  s16* __restrict__ Cb,
                                                  const float* __restrict__ bias,
                                                  const float* __restrict__ resid,
                                                  int flags, int tiles_y){
  __shared__ s16 lds[2*3*8192];   // [buf][slot: A0,A1,B][128*64]
  int t = threadIdx.x;
  int tx, ty; xcd_tile(tiles_y, tx, ty);
  int m0 = ty * 256, n0 = tx * 128;
  int w = t >> 6, lane = t & 63;
  int wm = w >> 2, wn = w & 3;         // 2M x 4N
  int lrow = lane & 15, lq = lane >> 4;
  int s = lrow & 7;

  int grow = t >> 3;
  int g = (t & 7) ^ (grow & 7);
  const s16* Ag = A  + (size_t)(m0 + grow) * K + g*8;
  const s16* Bg = Bt + (size_t)(n0 + grow) * K + g*8;
  int wo = w * 512;

  int abase = (wm*64 + lrow) * 64;
  int bbase = (wn*32 + lrow) * 64;
  int sw0 = ((lq ^ s) << 3);
  int sw1 = (((4 + lq) ^ s) << 3);

  f32x4 acc[2][4][2];                  // [mh][m][nj]
  #pragma unroll
  for (int a = 0; a < 2; ++a)
    #pragma unroll
    for (int b = 0; b < 4; ++b)
      #pragma unroll
      for (int c = 0; c < 2; ++c) acc[a][b][c] = (f32x4){0.f,0.f,0.f,0.f};

  short8 afA[2][4], afB[2][4];         // A0 / A1 frags
  short8 bfE[2][2], bfO[2][2];         // B frags, even/odd tile parity

#define STG_A(buf,h,kt) do{ \
    gl2lds16(Ag + (size_t)((h)*128    )*K + (kt)*64, lds + ((buf)*3+(h))*8192 + wo); \
    gl2lds16(Ag + (size_t)((h)*128+ 64)*K + (kt)*64, lds + ((buf)*3+(h))*8192 + 4096 + wo); }while(0)
#define STG_B(buf,kt) do{ \
    gl2lds16(Bg + (size_t)0*K  + (kt)*64, lds + ((buf)*3+2)*8192 + wo); \
    gl2lds16(Bg + (size_t)64*K + (kt)*64, lds + ((buf)*3+2)*8192 + 4096 + wo); }while(0)
#define RD_AH(buf,mh,dst) do{ const s16* p_ = lds + ((buf)*3+(mh))*8192 + abase; \
    _Pragma("unroll") for (int m_ = 0; m_ < 4; ++m_){ \
      dst[0][m_] = *(const short8*)(p_ + m_*1024 + sw0); \
      dst[1][m_] = *(const short8*)(p_ + m_*1024 + sw1); } }while(0)
#define RD_BH(buf,dst) do{ const s16* p_ = lds + ((buf)*3+2)*8192 + bbase; \
    _Pragma("unroll") for (int n_ = 0; n_ < 2; ++n_){ \
      dst[0][n_] = *(const short8*)(p_ + n_*1024 + sw0); \
      dst[1][n_] = *(const short8*)(p_ + n_*1024 + sw1); } }while(0)
#define MFMA_H(mh,A_,B_) do{ __builtin_amdgcn_s_setprio(1); \
    _Pragma("unroll") for (int kk_ = 0; kk_ < 2; ++kk_) \
      _Pragma("unroll") for (int m_ = 0; m_ < 4; ++m_) \
        _Pragma("unroll") for (int n_ = 0; n_ < 2; ++n_) \
          acc[mh][m_][n_] = __builtin_amdgcn_mfma_f32_16x16x32_bf16( \
              A_[kk_][m_], B_[kk_][n_], acc[mh][m_][n_], 0, 0, 0); \
    __builtin_amdgcn_s_setprio(0); }while(0)

  int NT = K >> 6;
  // prologue: tile0 {A0,B,A1} + tile1 {A0,B}; retire tile0; preload frags
  STG_A(0,0,0); STG_B(0,0); STG_A(0,1,0);
  STG_A(1,0,1); STG_B(1,1);
  VMW(4); BARR();
  RD_AH(0,0,afA); RD_BH(0,bfE);

  for (int it = 0; it < (NT-2)/2; ++it){
    int kt = 2*it;
    // tile kt (cb=0, CUR=bfE, NXT=bfO)
    STG_A(1,1,kt+1);
    BARR(); RD_AH(0,1,afB); MFMA_H(0,afA,bfE);
    STG_A(0,0,kt+2); STG_B(0,kt+2);
    VMW(4);
    BARR(); RD_AH(1,0,afA); RD_BH(1,bfO); MFMA_H(1,afB,bfE);
    // tile kt+1 (cb=1, CUR=bfO, NXT=bfE)
    STG_A(0,1,kt+2);
    BARR(); RD_AH(1,1,afB); MFMA_H(0,afA,bfO);
    STG_A(1,0,kt+3); STG_B(1,kt+3);
    VMW(4);
    BARR(); RD_AH(0,0,afA); RD_BH(0,bfE); MFMA_H(1,afB,bfO);
  }
  { // tile NT-2 (cb=0): stage only A1(NT-1); drain at P2
    STG_A(1,1,NT-1);
    BARR(); RD_AH(0,1,afB); MFMA_H(0,afA,bfE);
    VMW(0);
    BARR(); RD_AH(1,0,afA); RD_BH(1,bfO); MFMA_H(1,afB,bfE);
    // tile NT-1 (cb=1): pure compute
    BARR(); RD_AH(1,1,afB); MFMA_H(0,afA,bfO);
    MFMA_H(1,afB,bfO);
  }
#undef STG_A
#undef STG_B
#undef RD_AH
#undef RD_BH
#undef MFMA_H

  bool do_gelu = flags & 1;
  bool out_bf = flags & 2;
  #pragma unroll
  for (int nj = 0; nj < 2; ++nj){
    int col = n0 + wn*32 + nj*16 + lrow;
    float bcol = bias ? bias[col] : 0.f;
    #pragma unroll
    for (int mh = 0; mh < 2; ++mh){
      #pragma unroll
      for (int m = 0; m < 4; ++m){
        int row_base = m0 + wm*64 + mh*128 + m*16 + lq*4;
        #pragma unroll
        for (int r = 0; r < 4; ++r){
          int grow_ = row_base + r;
          float val = acc[mh][m][nj][r] + bcol;
          if (do_gelu) val = 0.5f * val * (1.f + erff(val * 0.70710678118654752f));
          if (resid) val += resid[(size_t)grow_ * N + col];
          if (out_bf) Cb[(size_t)grow_ * N + col] = f2bf(val);
          else        Cf[(size_t)grow_ * N + col] = val;
        }
      }
    }
  }
}

// ---------------- retention 2a (per batch): U_t[dv][dk] = (d_k*k (x) v)^T ----
// grid 512 = h(8) + n(64); k,v from fused qkv (row stride 4096)
__global__ __launch_bounds__(256,2) void ret_chunksum(const s16* __restrict__ k,
                                                      const s16* __restrict__ v,
                                                      s16* __restrict__ U){
  int bi = blockIdx.x;
  int h = bi & 7, n = bi >> 3;
  int t = threadIdx.x;
  __shared__ s16 ks[128*72];   // ks[dk][s], d_k decay folded
  __shared__ s16 vs[256*72];   // vs[dv][s]
  float log2b = log2f(1.f - exp2f(-5.f - (float)h));
  const s16* kbase = k + (size_t)(n*64)*4096 + h*128;
  const s16* vbase = v + (size_t)(n*64)*4096 + h*256;
  #pragma unroll
  for (int i = 0; i < 4; ++i){
    int e = i*2048 + t*8;
    int s = e >> 7, dk = e & 127;
    int4 kv = *(const int4*)(kbase + (size_t)s*4096 + dk);
    float f[8]; unpack8(kv, f);
    float dec = exp2f(log2b * (float)(63 - s));
    #pragma unroll
    for (int j = 0; j < 8; ++j) ks[(dk+j)*72 + s] = f2bf(f[j]*dec);
  }
  #pragma unroll
  for (int i = 0; i < 8; ++i){
    int e = i*2048 + t*8;
    int s = e >> 8, dv = e & 255;
    int4 vv = *(const int4*)(vbase + (size_t)s*4096 + dv);
    s16 tmp[8]; *(int4*)tmp = vv;
    #pragma unroll
    for (int j = 0; j < 8; ++j) vs[(dv+j)*72 + s] = tmp[j];
  }
  __syncthreads();
  int w = t >> 6, lane = t & 63;
  int m0w = w*64;   // dv rows, 4 tiles per wave
  int lrow = lane & 15, lq = lane >> 4;
  f32x4 acc[4][8];
  #pragma unroll
  for (int mi = 0; mi < 4; ++mi)
    #pragma unroll
    for (int ni = 0; ni < 8; ++ni) acc[mi][ni] = (f32x4){0.f,0.f,0.f,0.f};
  #pragma unroll
  for (int kk = 0; kk < 64; kk += 32){
    short8 af[4], bfr[8];
    #pragma unroll
    for (int mi = 0; mi < 4; ++mi)
      af[mi] = *(short8*)&vs[(m0w + mi*16 + lrow)*72 + kk + lq*8];
    #pragma unroll
    for (int ni = 0; ni < 8; ++ni)
      bfr[ni] = *(short8*)&ks[(ni*16 + lrow)*72 + kk + lq*8];
    #pragma unroll
    for (int mi = 0; mi < 4; ++mi)
      #pragma unroll
      for (int ni = 0; ni < 8; ++ni)
        acc[mi][ni] = __builtin_amdgcn_mfma_f32_16x16x32_bf16(af[mi], bfr[ni], acc[mi][ni], 0, 0, 0);
  }
  s16* Ub = U + ((size_t)(h*64 + n))*32768;
  #pragma unroll
  for (int mi = 0; mi < 4; ++mi)
    #pragma unroll
    for (int ni = 0; ni < 8; ++ni)
      #pragma unroll
      for (int r = 0; r < 4; ++r){
        int row = m0w + mi*16 + lq*4 + r;   // dv
        int col = ni*16 + lrow;             // dk
        Ub[(size_t)row*128 + col] = f2bf(acc[mi][ni][r]);
      }
}

// ---------------- retention 2b (per batch): in-place decay prefix scan -------
__global__ __launch_bounds__(256) void ret_scan(s16* __restrict__ US){
  int tid = blockIdx.x*256 + threadIdx.x;       // 32768 threads
  int h = tid >> 12;
  int rem = tid & 4095;
  int dv = rem >> 4, dk0 = (rem & 15)*8;
  float log2b = log2f(1.f - exp2f(-5.f - (float)h));
  float dc = exp2f(log2b * 64.f);
  s16* base = US + (size_t)h*64*32768 + (size_t)dv*128 + dk0;
  float acc[8] = {0.f,0.f,0.f,0.f,0.f,0.f,0.f,0.f};
  #pragma unroll 4
  for (int n = 0; n < 64; ++n){
    s16* p = base + (size_t)n*32768;
    int4 u4 = *(const int4*)p;
    float uf[8]; unpack8(u4, uf);
    s16 sb[8];
    #pragma unroll
    for (int j = 0; j < 8; ++j) sb[j] = f2bf(acc[j]);
    *(int4*)p = *(int4*)sb;
    #pragma unroll
    for (int j = 0; j < 8; ++j) acc[j] = acc[j]*dc + uf[j];
  }
}

// ---------------- retention fused (per batch): O = mask(qk^T)@v + dq*(q@S) ---
// grid 512 = h(8) + n(64). q,k,v from fused qkv (stride 4096); S_t [h][n][256][128]
__global__ __launch_bounds__(256,2) void ret_attn(const s16* __restrict__ q,
                                                  const s16* __restrict__ k,
                                                  const s16* __restrict__ v,
                                                  const s16* __restrict__ S,
                                                  s16* __restrict__ o){
  int bi = blockIdx.x;
  int h = bi & 7, n = bi >> 3;
  int t = threadIdx.x;
  int w = t >> 6, lane = t & 63;
  int lrow = lane & 15, lq = lane >> 4;
  float log2b = log2f(1.f - exp2f(-5.f - (float)h));
  __shared__ s16 As[64*72];    // masked scores, A-operand staging
  __shared__ s16 vs[256*72];   // v^T [dv][s]

  // stage v transposed
  const s16* vbase = v + (size_t)(n*64)*4096 + h*256;
  #pragma unroll
  for (int i = 0; i < 8; ++i){
    int e = i*2048 + t*8;
    int s = e >> 8, dv = e & 255;
    int4 vv = *(const int4*)(vbase + (size_t)s*4096 + dv);
    s16 tmp[8]; *(int4*)tmp = vv;
    #pragma unroll
    for (int j = 0; j < 8; ++j) vs[(dv+j)*72 + s] = tmp[j];
  }

  // phase 1: wave w computes A[:, 16w:16w+16] = q @ k^T, masked
  const s16* qbase = q + (size_t)(n*64)*4096 + h*128;
  const s16* kbase = k + (size_t)(n*64)*4096 + h*128;
  short8 qf[4][4];   // [row-tile][kstep], reused in phase 2
  #pragma unroll
  for (int ti = 0; ti < 4; ++ti)
    #pragma unroll
    for (int c = 0; c < 4; ++c)
      qf[ti][c] = *(const short8*)(qbase + (size_t)(ti*16 + lrow)*4096 + c*32 + lq*8);
  short8 kf[4];
  #pragma unroll
  for (int c = 0; c < 4; ++c)
    kf[c] = *(const short8*)(kbase + (size_t)(16*w + lrow)*4096 + c*32 + lq*8);
  #pragma unroll
  for (int ti = 0; ti < 4; ++ti){
    f32x4 acc_a = (f32x4){0.f,0.f,0.f,0.f};
    #pragma unroll
    for (int c = 0; c < 4; ++c)
      acc_a = __builtin_amdgcn_mfma_f32_16x16x32_bf16(qf[ti][c], kf[c], acc_a, 0, 0, 0);
    #pragma unroll
    for (int r = 0; r < 4; ++r){
      int ti_idx = ti*16 + lq*4 + r;
      int s_idx = 16*w + lrow;
      int d = ti_idx - s_idx;
      float val = (d >= 0) ? acc_a[r] * exp2f(log2b * (float)d) : 0.f;
      As[ti_idx*72 + s_idx] = f2bf(val);
    }
  }
  __syncthreads();

  // phase 2: wave w owns dv cols [64w, 64w+64)
  f32x4 acc[4][4];
  #pragma unroll
  for (int mi = 0; mi < 4; ++mi)
    #pragma unroll
    for (int nj = 0; nj < 4; ++nj) acc[mi][nj] = (f32x4){0.f,0.f,0.f,0.f};

  // q @ S  (K = 128)
  const s16* Sbase = S + ((size_t)(h*64 + n)*256 + w*64)*128;
  #pragma unroll
  for (int c = 0; c < 4; ++c){
    short8 bf[4];
    #pragma unroll
    for (int nj = 0; nj < 4; ++nj)
      bf[nj] = *(const short8*)(Sbase + (size_t)(nj*16 + lrow)*128 + c*32 + lq*8);
    #pragma unroll
    for (int mi = 0; mi < 4; ++mi)
      #pragma unroll
      for (int nj = 0; nj < 4; ++nj)
        acc[mi][nj] = __builtin_amdgcn_mfma_f32_16x16x32_bf16(qf[mi][c], bf[nj], acc[mi][nj], 0, 0, 0);
  }
  // scale by d_q = b^(row+1)
  #pragma unroll
  for (int mi = 0; mi < 4; ++mi){
    #pragma unroll
    for (int r = 0; r < 4; ++r){
      float dq = exp2f(log2b * (float)(mi*16 + lq*4 + r + 1));
      #pragma unroll
      for (int nj = 0; nj < 4; ++nj) acc[mi][nj][r] *= dq;
    }
  }
  // A @ v  (K = 64)
  #pragma unroll
  for (int c = 0; c < 2; ++c){
    short8 af[4], bf[4];
    #pragma unroll
    for (int mi = 0; mi < 4; ++mi)
      af[mi] = *(short8*)&As[(mi*16 + lrow)*72 + c*32 + lq*8];
    #pragma unroll
    for (int nj = 0; nj < 4; ++nj)
      bf[nj] = *(short8*)&vs[(w*64 + nj*16 + lrow)*72 + c*32 + lq*8];
    #pragma unroll
    for (int mi = 0; mi < 4; ++mi)
      #pragma unroll
      for (int nj = 0; nj < 4; ++nj)
        acc[mi][nj] = __builtin_amdgcn_mfma_f32_16x16x32_bf16(af[mi], bf[nj], acc[mi][nj], 0, 0, 0);
  }
  // write O
  s16* obase = o + (size_t)(n*64)*2048 + h*256;
  #pragma unroll
  for (int mi = 0; mi < 4; ++mi)
    #pragma unroll
    for (int nj = 0; nj < 4; ++nj)
      #pragma unroll
      for (int r = 0; r < 4; ++r){
        int row = mi*16 + lq*4 + r;
        int col = w*64 + nj*16 + lrow;
        obase[(size_t)row*2048 + col] = f2bf(acc[mi][nj][r]);
      }
}

extern "C" void kernel_launch(void* const* d_in, const int* in_sizes, int n_in,
                              void* d_out, int out_size, void* d_ws, size_t ws_size,
                              hipStream_t stream) {
  (void)in_sizes; (void)n_in; (void)out_size; (void)ws_size;
  const float* x     = (const float*)d_in[0];
  const float* ln1_w = (const float*)d_in[1];
  const float* ln1_b = (const float*)d_in[2];
  const float* Wq    = (const float*)d_in[3];
  const float* Wk    = (const float*)d_in[4];
  const float* Wv    = (const float*)d_in[5];
  const float* Wo    = (const float*)d_in[6];
  const float* ln2_w = (const float*)d_in[7];
  const float* ln2_b = (const float*)d_in[8];
  const float* W1    = (const float*)d_in[9];
  const float* b1    = (const float*)d_in[10];
  const float* W2    = (const float*)d_in[11];
  const float* b2    = (const float*)d_in[12];
  float* out = (float*)d_out;
  char* ws = (char*)d_ws;

  // ---- static arena, peak 172 MB (lifetime-aliased) ----
  const size_t MB = 1ull << 20;
  s16* Wqkv_t = (s16*)(ws + 0*MB);   // [0,8)  rows: 0-1023 q, 1024-2047 k, 2048-4095 v
  s16* Wo_t = (s16*)(ws + 8*MB);     // [8,12)
  s16* W1_t = (s16*)(ws + 12*MB);    // [12,20)
  s16* W2_t = (s16*)(ws + 20*MB);    // [20,28)
  s16* hbuf = (s16*)(ws + 28*MB);    // [28,44)  dead after QKV gemm
  s16* h2   = (s16*)(ws + 28*MB);    // [28,44)  alias dead hbuf (post-retention)
  s16* qkv  = (s16*)(ws + 44*MB);    // [44,108) [8192,4096] bf16, dead after ret_attn(b1)
  float* x1 = (float*)(ws + 44*MB);  // [44,76)  alias dead qkv head (post-retention)
  s16* fb   = (s16*)(ws + 76*MB);    // [76,140) alias dead qkv tail + US (FFN acts)
  s16* US   = (s16*)(ws + 108*MB);   // [108,140) bf16 per-batch U->S (in-place scan)
  s16* ob   = (s16*)(ws + 140*MB);   // [140,172)

  // weight transpose-convert (DK^-0.5 folded into Wq)
  conv_t<<<dim3(32,32),  256, 0, stream>>>(Wq, Wqkv_t, 1024, 1024, 0.08838834764831845f);
  conv_t<<<dim3(32,32),  256, 0, stream>>>(Wk, Wqkv_t + (size_t)1024*1024, 1024, 1024, 1.f);
  conv_t<<<dim3(64,32),  256, 0, stream>>>(Wv, Wqkv_t + (size_t)2048*1024, 1024, 2048, 1.f);
  conv_t<<<dim3(32,64),  256, 0, stream>>>(Wo, Wo_t, 2048, 1024, 1.f);
  conv_t<<<dim3(128,32), 256, 0, stream>>>(W1, W1_t, 1024, 4096, 1.f);
  conv_t<<<dim3(32,128), 256, 0, stream>>>(W2, W2_t, 4096, 1024, 1.f);

  ln_bf16<<<8192, 256, 0, stream>>>(x, ln1_w, ln1_b, hbuf);

  // fused QKV: [8192,4096] = hbuf @ Wqkv^T  (256^2 pipelined, 512 blocks)
  gemm256<<<512, 512, 0, stream>>>(hbuf, Wqkv_t, 4096, 1024, qkv, nullptr, 0, 32);

  for (int b = 0; b < 2; ++b){
    const s16* q_b = qkv + (size_t)b*4096*4096;
    const s16* k_b = q_b + 1024;
    const s16* v_b = q_b + 2048;
    s16* ob_b = ob + (size_t)b*4096*2048;
    ret_chunksum<<<512, 256, 0, stream>>>(k_b, v_b, US);
    ret_scan<<<128, 256, 0, stream>>>(US);
    ret_attn<<<512, 256, 0, stream>>>(q_b, k_b, v_b, US, ob_b);
  }

  // Wo: x1 = x + ob @ Wo^T   (256x128 pipelined, 256 blocks, tiles_y=32)
  gemm256h<<<256, 512, 0, stream>>>(ob, Wo_t, 1024, 2048, x1, nullptr, nullptr, x, 0, 32);
  ln_bf16<<<8192, 256, 0, stream>>>(x1, ln2_w, ln2_b, h2);

  // FFN: fb = gelu(h2 @ W1^T + b1)  [8192,4096]  (256^2 pipelined)
  gemm256<<<512, 512, 0, stream>>>(h2, W1_t, 4096, 1024, fb, b1, 1, 32);
  // out = x1 + b2 + fb @ W2^T   (256x128 pipelined, 256 blocks, K=4096)
  gemm256h<<<256, 512, 0, stream>>>(fb, W2_t, 1024, 4096, out, nullptr, b2, x1, 0, 32);
}